// Round 1
// baseline (351.966 us; speedup 1.0000x reference)
//
#include <hip/hip_runtime.h>
#include <math.h>

#define NB 8192     // batch
#define ND 128      // dim
#define BI 32       // rows per block
#define NJ 256      // cols per tile
#define NTILE 8     // tiles per block -> 2048 cols per block
#define KC 32       // k-chunk staged in LDS
#define CSPLIT 4    // column splits across blocks
#define PART_STRIDE 6

static __device__ __forceinline__ float wave_sum_f(float v) {
  #pragma unroll
  for (int off = 1; off < 64; off <<= 1) v += __shfl_xor(v, off);
  return v;
}

// online logsumexp in base-2: state (m, s); x is log2-domain logit
static __device__ __forceinline__ void lse_update(float& m, float& s, float x) {
  if (x > m) {
    s = s * exp2f(m - x) + 1.0f;   // exp2f(-inf)=0 handles first element
    m = x;
  } else {
    s += exp2f(x - m);
  }
}

static __device__ __forceinline__ void lse_merge(float& m, float& s, float m2, float s2) {
  float M = fmaxf(m, m2);
  float t1 = (m  > -INFINITY) ? s  * exp2f(m  - M) : 0.0f;
  float t2 = (m2 > -INFINITY) ? s2 * exp2f(m2 - M) : 0.0f;
  m = M;
  s = t1 + t2;
}

__global__ void k_norms(const float* __restrict__ emb, float* __restrict__ inv) {
  const int l = threadIdx.x & 63;
  const int w = threadIdx.x >> 6;
  const int row = blockIdx.x * 4 + w;
  float x0 = emb[row * ND + l];
  float x1 = emb[row * ND + 64 + l];
  float ss = wave_sum_f(x0 * x0 + x1 * x1);
  if (l == 0) {
    float n = fmaxf(sqrtf(ss), 1e-12f);
    inv[row] = 1.0f / n;
  }
}

__global__ __launch_bounds__(256) void k_main(const float* __restrict__ emb,
                                              const int* __restrict__ labels,
                                              const float* __restrict__ inv,
                                              float* __restrict__ part) {
  // gamma * log2(e): logits computed directly in log2 domain
  const float G2 = 256.0f * 1.4426950408889634f;

  __shared__ __align__(16) float A_lds[ND][BI];   // [k][row], 16 KB
  __shared__ __align__(16) float B_lds[KC][NJ];   // [k][col], 32 KB

  const int tid = threadIdx.x;
  const int l = tid & 63;
  const int w = tid >> 6;
  const int rt = blockIdx.x >> 2;          // row tile
  const int cs = blockIdx.x & (CSPLIT - 1); // column split
  const int row0 = rt * BI;
  const int col0 = cs * (NJ * NTILE);

  // ---- stage A tile (once): A_lds[k][row] = e_norm[row0+row][k]
  {
    const int row = tid >> 3;
    const int seg = tid & 7;
    const int rg = row0 + row;
    const float invr = inv[rg];
    const float4* s4 = reinterpret_cast<const float4*>(&emb[(size_t)rg * ND + seg * 16]);
    #pragma unroll
    for (int q = 0; q < 4; ++q) {
      float4 f = s4[q];
      int kb = seg * 16 + q * 4;
      A_lds[kb + 0][row] = f.x * invr;
      A_lds[kb + 1][row] = f.y * invr;
      A_lds[kb + 2][row] = f.z * invr;
      A_lds[kb + 3][row] = f.w * invr;
    }
  }

  const int wrow = row0 + w * 8;   // this wave's first row
  int lr[8];
  #pragma unroll
  for (int u = 0; u < 8; ++u) lr[u] = labels[wrow + u];

  float mp[8], sp[8], mn[8], sn[8];
  int np[8];
  #pragma unroll
  for (int u = 0; u < 8; ++u) {
    mp[u] = -INFINITY; sp[u] = 0.f;
    mn[u] = -INFINITY; sn[u] = 0.f;
    np[u] = 0;
  }

  for (int tile = 0; tile < NTILE; ++tile) {
    const int colg0 = col0 + tile * NJ;
    const float invc = inv[colg0 + tid];   // column this thread stages
    int lc[4];
    #pragma unroll
    for (int v = 0; v < 4; ++v) lc[v] = labels[colg0 + l * 4 + v];

    float acc[8][4];
    #pragma unroll
    for (int u = 0; u < 8; ++u)
      #pragma unroll
      for (int v = 0; v < 4; ++v) acc[u][v] = 0.f;

    for (int kc = 0; kc < ND / KC; ++kc) {
      __syncthreads();   // previous chunk compute / previous tile done
      // ---- stage B chunk: thread tid owns column (colg0+tid), dims [kc*KC, kc*KC+KC)
      {
        const float4* s4 =
            reinterpret_cast<const float4*>(&emb[(size_t)(colg0 + tid) * ND + kc * KC]);
        #pragma unroll
        for (int q = 0; q < 8; ++q) {
          float4 f = s4[q];
          int kk = q * 4;
          B_lds[kk + 0][tid] = f.x * invc;   // lane-stride 4B writes: conflict-free
          B_lds[kk + 1][tid] = f.y * invc;
          B_lds[kk + 2][tid] = f.z * invc;
          B_lds[kk + 3][tid] = f.w * invc;
        }
      }
      __syncthreads();
      // ---- compute: 8 rows x 4 cols micro-tile per thread
      #pragma unroll 4
      for (int k = 0; k < KC; ++k) {
        const float4* Ap = reinterpret_cast<const float4*>(&A_lds[kc * KC + k][w * 8]);
        float4 a0 = Ap[0];   // broadcast within wave (all lanes same ty) -> free
        float4 a1 = Ap[1];
        const float4* Bp = reinterpret_cast<const float4*>(&B_lds[k][l * 4]);
        float4 b = Bp[0];    // 16B/lane stride: 2-way bank aliasing = free
        float av[8] = {a0.x, a0.y, a0.z, a0.w, a1.x, a1.y, a1.z, a1.w};
        float bv[4] = {b.x, b.y, b.z, b.w};
        #pragma unroll
        for (int u = 0; u < 8; ++u)
          #pragma unroll
          for (int v = 0; v < 4; ++v)
            acc[u][v] = fmaf(av[u], bv[v], acc[u][v]);
      }
    }

    // ---- fused epilogue: fold this tile's 8x4 sim block into per-row LSE states
    #pragma unroll
    for (int v = 0; v < 4; ++v) {
      const int cg = colg0 + l * 4 + v;
      #pragma unroll
      for (int u = 0; u < 8; ++u) {
        const float s = acc[u][v];
        const int rg = wrow + u;
        if (lc[v] == lr[u]) {
          if (cg != rg) {  // diagonal always falls in the equal-label branch
            float x = G2 * fmaxf(1.25f - s, 0.f) * (0.75f - s);  // -g*ap*(s-0.75), log2 dom
            lse_update(mp[u], sp[u], x);
            np[u]++;
          }
        } else {
          float x = G2 * fmaxf(s + 0.25f, 0.f) * (s - 0.25f);    // g*an*(s-0.25), log2 dom
          lse_update(mn[u], sn[u], x);
        }
      }
    }
  }

  // ---- butterfly-merge lane partials (each wave owns its 8 rows), write block partials
  #pragma unroll
  for (int u = 0; u < 8; ++u) {
    #pragma unroll
    for (int off = 1; off < 64; off <<= 1) {
      float m2, s2;
      m2 = __shfl_xor(mp[u], off); s2 = __shfl_xor(sp[u], off);
      lse_merge(mp[u], sp[u], m2, s2);
      m2 = __shfl_xor(mn[u], off); s2 = __shfl_xor(sn[u], off);
      lse_merge(mn[u], sn[u], m2, s2);
      np[u] += __shfl_xor(np[u], off);
    }
    if (l == 0) {
      float* p = &part[((size_t)(wrow + u) * CSPLIT + cs) * PART_STRIDE];
      p[0] = mp[u]; p[1] = sp[u]; p[2] = mn[u]; p[3] = sn[u];
      p[4] = (float)np[u]; p[5] = 0.f;
    }
  }
}

__global__ void k_rows(const float* __restrict__ part, float* __restrict__ bsum) {
  const float LN2F = 0.6931471805599453f;
  const int row = blockIdx.x * 256 + threadIdx.x;
  float mp = -INFINITY, sp = 0.f, mn = -INFINITY, sn = 0.f, npf = 0.f;
  #pragma unroll
  for (int c = 0; c < CSPLIT; ++c) {
    const float* p = &part[((size_t)row * CSPLIT + c) * PART_STRIDE];
    lse_merge(mp, sp, p[0], p[1]);
    lse_merge(mn, sn, p[2], p[3]);
    npf += p[4];
  }
  const int npi = (int)(npf + 0.5f);
  const bool valid = (npi > 0) && (npi < NB - 1);
  float val = 0.f;
  if (valid) {
    float lp  = LN2F * (mp + log2f(sp));
    float lnn = LN2F * (mn + log2f(sn));
    float x = lp + lnn;
    val = fmaxf(x, 0.f) + log1pf(expf(-fabsf(x)));  // stable softplus
  }
  float cnt = valid ? 1.f : 0.f;
  val = wave_sum_f(val);
  cnt = wave_sum_f(cnt);
  __shared__ float svals[4], scnts[4];
  const int l = threadIdx.x & 63, w = threadIdx.x >> 6;
  if (l == 0) { svals[w] = val; scnts[w] = cnt; }
  __syncthreads();
  if (threadIdx.x == 0) {
    bsum[blockIdx.x * 2 + 0] = svals[0] + svals[1] + svals[2] + svals[3];
    bsum[blockIdx.x * 2 + 1] = scnts[0] + scnts[1] + scnts[2] + scnts[3];
  }
}

__global__ void k_final(const float* __restrict__ bsum, float* __restrict__ out) {
  const int t = threadIdx.x;
  float s = 0.f, c = 0.f;
  if (t < 32) { s = bsum[t * 2]; c = bsum[t * 2 + 1]; }
  s = wave_sum_f(s);
  c = wave_sum_f(c);
  if (t == 0) out[0] = s / fmaxf(c, 1.f);
}

extern "C" void kernel_launch(void* const* d_in, const int* in_sizes, int n_in,
                              void* d_out, int out_size, void* d_ws, size_t ws_size,
                              hipStream_t stream) {
  const float* emb = (const float*)d_in[0];
  const int* labels = (const int*)d_in[1];
  float* out = (float*)d_out;
  char* ws = (char*)d_ws;

  float* part = (float*)ws;                              // 8192*4*6 floats = 768 KB
  float* bsum = (float*)(ws + (size_t)NB * CSPLIT * PART_STRIDE * 4);  // 32*2 floats
  float* inv  = (float*)(ws + (size_t)NB * CSPLIT * PART_STRIDE * 4 + 256);

  k_norms<<<NB / 4, 256, 0, stream>>>(emb, inv);
  k_main<<<(NB / BI) * CSPLIT, 256, 0, stream>>>(emb, labels, inv, part);
  k_rows<<<NB / 256, 256, 0, stream>>>(part, bsum);
  k_final<<<1, 64, 0, stream>>>(bsum, out);
}

// Round 3
// 177.277 us; speedup vs baseline: 1.9854x; 1.9854x over previous
//
#include <hip/hip_runtime.h>
#include <math.h>

#define NB 8192
#define ND 128
#define BT 128       // tile edge (rows and cols)
#define CSPLIT 8     // column splits (blocks per row-tile)
#define CTILES 8     // col tiles iterated per block: 8*128*8 = 8192
#define PART_STRIDE 6

typedef unsigned short u16;
typedef unsigned int u32;
typedef __attribute__((ext_vector_type(8))) short bf16x8;
typedef __attribute__((ext_vector_type(4))) float f32x4;

static __device__ __forceinline__ void gload16(const void* g, void* l) {
  __builtin_amdgcn_global_load_lds(
      (const __attribute__((address_space(1))) u32*)g,
      (__attribute__((address_space(3))) u32*)l, 16, 0, 0);
}

static __device__ __forceinline__ u16 f2bf(float f) {
  u32 u = __float_as_uint(f);
  u32 r = (u + 0x7FFF + ((u >> 16) & 1)) >> 16;   // RNE, no NaN inputs here
  return (u16)r;
}

static __device__ __forceinline__ float wave_sum_f(float v) {
  #pragma unroll
  for (int off = 1; off < 64; off <<= 1) v += __shfl_xor(v, off);
  return v;
}

static __device__ __forceinline__ void lse_merge(float& m, float& s, float m2, float s2) {
  float M = fmaxf(m, m2);
  float t1 = (m  > -INFINITY) ? s  * exp2f(m  - M) : 0.0f;
  float t2 = (m2 > -INFINITY) ? s2 * exp2f(m2 - M) : 0.0f;
  m = M;
  s = t1 + t2;
}

// ---- normalize rows + cast to bf16 ----------------------------------------
__global__ void k_prep(const float* __restrict__ emb, u16* __restrict__ e) {
  const int l = threadIdx.x & 63;
  const int w = threadIdx.x >> 6;
  const int row = blockIdx.x * 4 + w;
  const float2 v = reinterpret_cast<const float2*>(emb)[(size_t)row * 64 + l];
  float ss = wave_sum_f(v.x * v.x + v.y * v.y);
  const float inv = 1.0f / fmaxf(sqrtf(ss), 1e-12f);
  ushort2 o;
  o.x = f2bf(v.x * inv);
  o.y = f2bf(v.y * inv);
  reinterpret_cast<ushort2*>(e)[(size_t)row * 64 + l] = o;
}

// ---- MFMA sim tiles + fused screened-LSE epilogue -------------------------
__global__ __launch_bounds__(256, 2) void k_main(const u16* __restrict__ e,
                                                 const int* __restrict__ labels,
                                                 float* __restrict__ part) {
  const float G2 = 369.3299304675766f;   // gamma * log2(e)
  __shared__ char A_lds[BT * 256];       // 32 KB, [row][swizzled 16B slot]
  __shared__ char B_lds[BT * 256];       // 32 KB

  const int tid = threadIdx.x;
  const int l = tid & 63;
  const int w = tid >> 6;
  const int lr_ = l & 15;
  const int lg = l >> 4;
  const int wm = w >> 1, wn = w & 1;     // wave -> 64x64 quadrant
  const int rt = blockIdx.x >> 3;
  const int cs = blockIdx.x & 7;
  const int row0 = rt * BT;
  const int csbase = cs * (CTILES * BT);

  // row labels for this lane's 16 row-slots
  int lrl[16];
  #pragma unroll
  for (int m = 0; m < 4; ++m)
    #pragma unroll
    for (int j = 0; j < 4; ++j)
      lrl[m * 4 + j] = labels[row0 + wm * 64 + m * 16 + lg * 4 + j];

  // stage A tile once; swizzled SOURCE + linear LDS dest (rule 21)
  #pragma unroll
  for (int i = 0; i < 8; ++i) {
    const int rr = w * 32 + i * 4 + lg;
    const int srcslot = lr_ ^ (rr & 15);
    gload16(e + (size_t)(row0 + rr) * ND + srcslot * 8, A_lds + w * 8192 + i * 1024);
  }
  // stage B tile 0
  #pragma unroll
  for (int i = 0; i < 8; ++i) {
    const int rr = w * 32 + i * 4 + lg;
    const int srcslot = lr_ ^ (rr & 15);
    gload16(e + (size_t)(csbase + rr) * ND + srcslot * 8, B_lds + w * 8192 + i * 1024);
  }

  float mp[16], sp[16], mn_[16], sn_[16];
  int np[16];
  #pragma unroll
  for (int q = 0; q < 16; ++q) {
    mp[q] = -INFINITY; sp[q] = 0.f; mn_[q] = -INFINITY; sn_[q] = 0.f; np[q] = 0;
  }

  __syncthreads();

  for (int it = 0; it < CTILES; ++it) {
    const int colg0 = csbase + it * BT;
    int lcl[4], cgd[4];
    const int dRC = (colg0 + wn * 64) - (row0 + wm * 64);
    #pragma unroll
    for (int n = 0; n < 4; ++n) {
      lcl[n] = labels[colg0 + wn * 64 + n * 16 + lr_];
      cgd[n] = n * 16 + lr_ + dRC;
    }

    f32x4 acc[4][4];
    #pragma unroll
    for (int m = 0; m < 4; ++m)
      #pragma unroll
      for (int n = 0; n < 4; ++n)
        #pragma unroll
        for (int q = 0; q < 4; ++q) acc[m][n][q] = 0.f;

    #pragma unroll
    for (int ks = 0; ks < 4; ++ks) {
      const int kslot = (ks * 4 + lg) ^ lr_;   // read-side swizzle
      bf16x8 af[4], bfr[4];
      #pragma unroll
      for (int m = 0; m < 4; ++m)
        af[m] = *(const bf16x8*)(A_lds + (wm * 64 + m * 16 + lr_) * 256 + kslot * 16);
      #pragma unroll
      for (int n = 0; n < 4; ++n)
        bfr[n] = *(const bf16x8*)(B_lds + (wn * 64 + n * 16 + lr_) * 256 + kslot * 16);
      #pragma unroll
      for (int m = 0; m < 4; ++m)
        #pragma unroll
        for (int n = 0; n < 4; ++n)
          acc[m][n] = __builtin_amdgcn_mfma_f32_16x16x32_bf16(af[m], bfr[n], acc[m][n], 0, 0, 0);
    }

    __syncthreads();   // all waves finished reading B

    if (it + 1 < CTILES) {   // issue next B tile; lands during epilogue (T14)
      const int colg1 = csbase + (it + 1) * BT;
      #pragma unroll
      for (int i = 0; i < 8; ++i) {
        const int rr = w * 32 + i * 4 + lg;
        const int srcslot = lr_ ^ (rr & 15);
        gload16(e + (size_t)(colg1 + rr) * ND + srcslot * 8, B_lds + w * 8192 + i * 1024);
      }
    }

    // fused epilogue: screened online-LSE over this 128x128 sim tile
    #pragma unroll
    for (int m = 0; m < 4; ++m) {
      #pragma unroll
      for (int j = 0; j < 4; ++j) {
        const int slot = m * 4 + j;
        const int lrow = lrl[slot];
        const int rrel = m * 16 + lg * 4 + j;
        #pragma unroll
        for (int n = 0; n < 4; ++n) {
          const float sv = acc[m][n][j];
          const bool eq = (lcl[n] == lrow);
          const float t2 = sv + 0.25f;
          const float xn = G2 * fmaxf(t2, 0.f) * (t2 - 0.5f);  // log2-domain neg logit
          // screen: drop if >30 below running max (rel contribution < 2^-30)
          const bool updn = (!eq) && (xn > mn_[slot] - 30.f);
          if (updn) {
            if (xn > mn_[slot]) { sn_[slot] = sn_[slot] * exp2f(mn_[slot] - xn) + 1.f; mn_[slot] = xn; }
            else sn_[slot] += exp2f(xn - mn_[slot]);
          }
          const bool isp = eq && (rrel != cgd[n]);
          if (isp) {
            const float t1 = 1.25f - sv;
            const float xp = G2 * fmaxf(t1, 0.f) * (t1 - 0.5f);  // log2-domain pos logit
            if (xp > mp[slot]) { sp[slot] = sp[slot] * exp2f(mp[slot] - xp) + 1.f; mp[slot] = xp; }
            else sp[slot] += exp2f(xp - mp[slot]);
            np[slot]++;
          }
        }
      }
    }
    __syncthreads();   // staged B landed (vmcnt drained at barrier)
  }

  // ---- reduce the 16 lanes sharing each row (same lg group, xor over lr_)
  #pragma unroll
  for (int q = 0; q < 16; ++q) {
    #pragma unroll
    for (int off = 1; off < 16; off <<= 1) {
      float m2 = __shfl_xor(mp[q], off), s2 = __shfl_xor(sp[q], off);
      lse_merge(mp[q], sp[q], m2, s2);
      m2 = __shfl_xor(mn_[q], off); s2 = __shfl_xor(sn_[q], off);
      lse_merge(mn_[q], sn_[q], m2, s2);
      np[q] += __shfl_xor(np[q], off);
    }
  }

  // ---- FIX: merge the two column-half waves (wn=0,1) that share each row.
  // wn=1 publishes its 64-row states to LDS (A_lds is dead now), wn=0 merges
  // and writes the single combined partial. Round-2 bug: both waves wrote the
  // same part[] slot -> half the columns' contributions were lost per row.
  __syncthreads();                       // all LDS reads of A/B done
  float* S = (float*)A_lds;              // 2 * 64 rows * 5 floats = 2.5 KB
  if (wn == 1 && lr_ == 0) {
    #pragma unroll
    for (int m = 0; m < 4; ++m)
      #pragma unroll
      for (int j = 0; j < 4; ++j) {
        const int q = m * 4 + j;
        const int r = m * 16 + lg * 4 + j;
        float* p = S + (size_t)(wm * 64 + r) * 5;
        p[0] = mp[q]; p[1] = sp[q]; p[2] = mn_[q]; p[3] = sn_[q]; p[4] = (float)np[q];
      }
  }
  __syncthreads();
  if (wn == 0 && lr_ == 0) {
    #pragma unroll
    for (int m = 0; m < 4; ++m)
      #pragma unroll
      for (int j = 0; j < 4; ++j) {
        const int q = m * 4 + j;
        const int r = m * 16 + lg * 4 + j;
        const float* p = S + (size_t)(wm * 64 + r) * 5;
        lse_merge(mp[q], sp[q], p[0], p[1]);
        lse_merge(mn_[q], sn_[q], p[2], p[3]);
        np[q] += (int)p[4];
        const int row = row0 + wm * 64 + r;
        float* o = &part[((size_t)row * CSPLIT + cs) * PART_STRIDE];
        o[0] = mp[q]; o[1] = sp[q]; o[2] = mn_[q]; o[3] = sn_[q]; o[4] = (float)np[q];
      }
  }
}

// ---- merge column-split partials per row, softplus, block-reduce ----------
__global__ void k_rows(const float* __restrict__ part, float* __restrict__ bsum) {
  const float LN2F = 0.6931471805599453f;
  const int row = blockIdx.x * 256 + threadIdx.x;
  float mp = -INFINITY, sp = 0.f, mn = -INFINITY, sn = 0.f, npf = 0.f;
  #pragma unroll
  for (int c = 0; c < CSPLIT; ++c) {
    const float* p = &part[((size_t)row * CSPLIT + c) * PART_STRIDE];
    lse_merge(mp, sp, p[0], p[1]);
    lse_merge(mn, sn, p[2], p[3]);
    npf += p[4];
  }
  const int npi = (int)(npf + 0.5f);
  const bool valid = (npi > 0) && (npi < NB - 1);
  float val = 0.f;
  if (valid) {
    float lp  = LN2F * (mp + log2f(sp));
    float lnn = LN2F * (mn + log2f(sn));
    float x = lp + lnn;
    val = fmaxf(x, 0.f) + log1pf(expf(-fabsf(x)));  // stable softplus
  }
  float cnt = valid ? 1.f : 0.f;
  val = wave_sum_f(val);
  cnt = wave_sum_f(cnt);
  __shared__ float svals[4], scnts[4];
  const int l = threadIdx.x & 63, w = threadIdx.x >> 6;
  if (l == 0) { svals[w] = val; scnts[w] = cnt; }
  __syncthreads();
  if (threadIdx.x == 0) {
    bsum[blockIdx.x * 2 + 0] = svals[0] + svals[1] + svals[2] + svals[3];
    bsum[blockIdx.x * 2 + 1] = scnts[0] + scnts[1] + scnts[2] + scnts[3];
  }
}

__global__ void k_final(const float* __restrict__ bsum, float* __restrict__ out) {
  const int t = threadIdx.x;
  float s = 0.f, c = 0.f;
  if (t < 32) { s = bsum[t * 2]; c = bsum[t * 2 + 1]; }
  s = wave_sum_f(s);
  c = wave_sum_f(c);
  if (t == 0) out[0] = s / fmaxf(c, 1.f);
}

extern "C" void kernel_launch(void* const* d_in, const int* in_sizes, int n_in,
                              void* d_out, int out_size, void* d_ws, size_t ws_size,
                              hipStream_t stream) {
  const float* emb = (const float*)d_in[0];
  const int* labels = (const int*)d_in[1];
  float* out = (float*)d_out;
  char* ws = (char*)d_ws;

  float* part = (float*)ws;                        // 8192*8*6*4 = 1,572,864 B
  float* bsum = (float*)(ws + 1572864);            // 256 B
  u16*   ebf  = (u16*)(ws + 2097152);              // 2 MB bf16 normalized embeddings

  k_prep<<<NB / 4, 256, 0, stream>>>(emb, ebf);
  k_main<<<(NB / BT) * CSPLIT, 256, 0, stream>>>(ebf, labels, part);
  k_rows<<<NB / 256, 256, 0, stream>>>(part, bsum);
  k_final<<<1, 64, 0, stream>>>(bsum, out);
}

// Round 4
// 118.043 us; speedup vs baseline: 2.9817x; 1.5018x over previous
//
#include <hip/hip_runtime.h>
#include <math.h>

#define NB 8192
#define ND 128
#define BT 128       // tile edge (rows and cols)
#define CSPLIT 8     // column splits (blocks per row-tile)
#define CTILES 8     // col tiles iterated per block: 8*128*8 = 8192
#define PART_STRIDE 6

typedef unsigned short u16;
typedef unsigned int u32;
typedef __attribute__((ext_vector_type(8))) short bf16x8;
typedef __attribute__((ext_vector_type(4))) float f32x4;

#define G2 369.3299304675746f        // gamma * log2(e)
#define NEG_C (-23.083120654223414f) // -G2/16
#define SENT (-1e30f)                // finite "masked" sentinel (no NaN paths)

static __device__ __forceinline__ void gload16(const void* g, void* l) {
  __builtin_amdgcn_global_load_lds(
      (const __attribute__((address_space(1))) u32*)g,
      (__attribute__((address_space(3))) u32*)l, 16, 0, 0);
}

static __device__ __forceinline__ float fexp2(float x) {
  return __builtin_amdgcn_exp2f(x);   // single v_exp_f32; exp2(-huge)=0
}

static __device__ __forceinline__ u16 f2bf(float f) {
  u32 u = __float_as_uint(f);
  u32 r = (u + 0x7FFF + ((u >> 16) & 1)) >> 16;   // RNE
  return (u16)r;
}

static __device__ __forceinline__ float wave_sum_f(float v) {
  #pragma unroll
  for (int off = 1; off < 64; off <<= 1) v += __shfl_xor(v, off);
  return v;
}

static __device__ __forceinline__ void lse_merge(float& m, float& s, float m2, float s2) {
  float M = fmaxf(m, m2);
  float t1 = (m  > -INFINITY) ? s  * fexp2(m  - M) : 0.0f;
  float t2 = (m2 > -INFINITY) ? s2 * fexp2(m2 - M) : 0.0f;
  m = M;
  s = t1 + t2;
}

// ---- normalize rows + cast to bf16 ----------------------------------------
__global__ void k_prep(const float* __restrict__ emb, u16* __restrict__ e) {
  const int l = threadIdx.x & 63;
  const int w = threadIdx.x >> 6;
  const int row = blockIdx.x * 4 + w;
  const float2 v = reinterpret_cast<const float2*>(emb)[(size_t)row * 64 + l];
  float ss = wave_sum_f(v.x * v.x + v.y * v.y);
  const float inv = 1.0f / fmaxf(sqrtf(ss), 1e-12f);
  ushort2 o;
  o.x = f2bf(v.x * inv);
  o.y = f2bf(v.y * inv);
  reinterpret_cast<ushort2*>(e)[(size_t)row * 64 + l] = o;
}

// ---- MFMA sim tiles + branch-free fixed-base LSE epilogue -----------------
__global__ __launch_bounds__(256, 2) void k_main(const u16* __restrict__ e,
                                                 const int* __restrict__ labels,
                                                 float* __restrict__ part) {
  __shared__ char A_lds[BT * 256];       // 32 KB, [row][swizzled 16B slot]
  __shared__ char B_lds[BT * 256];       // 32 KB

  const int tid = threadIdx.x;
  const int l = tid & 63;
  const int w = tid >> 6;
  const int lr_ = l & 15;
  const int lg = l >> 4;
  const int wm = w >> 1, wn = w & 1;     // wave -> 64x64 quadrant
  const int rt = blockIdx.x >> 3;
  const int cs = blockIdx.x & 7;
  const int row0 = rt * BT;
  const int csbase = cs * (CTILES * BT);

  // row labels for this lane's 16 row-slots
  int lrl[16];
  #pragma unroll
  for (int m = 0; m < 4; ++m)
    #pragma unroll
    for (int j = 0; j < 4; ++j)
      lrl[m * 4 + j] = labels[row0 + wm * 64 + m * 16 + lg * 4 + j];

  // stage A tile once; swizzled SOURCE + linear LDS dest (rule 21)
  #pragma unroll
  for (int i = 0; i < 8; ++i) {
    const int rr = w * 32 + i * 4 + lg;
    const int srcslot = lr_ ^ (rr & 15);
    gload16(e + (size_t)(row0 + rr) * ND + srcslot * 8, A_lds + w * 8192 + i * 1024);
  }
  // stage B tile 0
  #pragma unroll
  for (int i = 0; i < 8; ++i) {
    const int rr = w * 32 + i * 4 + lg;
    const int srcslot = lr_ ^ (rr & 15);
    gload16(e + (size_t)(csbase + rr) * ND + srcslot * 8, B_lds + w * 8192 + i * 1024);
  }

  // negatives: fixed base en (starts 0; xn >= -23.08 so no underflow).
  // positives: defer-max base ep (sentinel), rescale only on >60 jumps.
  float en[16], sn[16], ep[16], sp[16];
  int np[16];
  #pragma unroll
  for (int q = 0; q < 16; ++q) {
    en[q] = 0.f; sn[q] = 0.f; ep[q] = SENT; sp[q] = 0.f; np[q] = 0;
  }

  __syncthreads();

  for (int it = 0; it < CTILES; ++it) {
    const int colg0 = csbase + it * BT;
    int lcl[4], cgd[4];
    const int dRC = (colg0 + wn * 64) - (row0 + wm * 64);
    #pragma unroll
    for (int n = 0; n < 4; ++n) {
      lcl[n] = labels[colg0 + wn * 64 + n * 16 + lr_];
      cgd[n] = n * 16 + lr_ + dRC;
    }

    f32x4 acc[4][4];
    #pragma unroll
    for (int m = 0; m < 4; ++m)
      #pragma unroll
      for (int n = 0; n < 4; ++n)
        #pragma unroll
        for (int q = 0; q < 4; ++q) acc[m][n][q] = 0.f;

    #pragma unroll
    for (int ks = 0; ks < 4; ++ks) {
      const int kslot = (ks * 4 + lg) ^ lr_;   // read-side swizzle
      bf16x8 af[4], bfr[4];
      #pragma unroll
      for (int m = 0; m < 4; ++m)
        af[m] = *(const bf16x8*)(A_lds + (wm * 64 + m * 16 + lr_) * 256 + kslot * 16);
      #pragma unroll
      for (int n = 0; n < 4; ++n)
        bfr[n] = *(const bf16x8*)(B_lds + (wn * 64 + n * 16 + lr_) * 256 + kslot * 16);
      #pragma unroll
      for (int m = 0; m < 4; ++m)
        #pragma unroll
        for (int n = 0; n < 4; ++n)
          acc[m][n] = __builtin_amdgcn_mfma_f32_16x16x32_bf16(af[m], bfr[n], acc[m][n], 0, 0, 0);
    }

    __syncthreads();   // all waves finished reading B

    if (it + 1 < CTILES) {   // issue next B tile; lands during epilogue (T14)
      const int colg1 = csbase + (it + 1) * BT;
      #pragma unroll
      for (int i = 0; i < 8; ++i) {
        const int rr = w * 32 + i * 4 + lg;
        const int srcslot = lr_ ^ (rr & 15);
        gload16(e + (size_t)(colg1 + rr) * ND + srcslot * 8, B_lds + w * 8192 + i * 1024);
      }
    }

    // ---- epilogue: straight-line negatives, ballot-guarded rare paths
    #pragma unroll
    for (int m = 0; m < 4; ++m) {
      #pragma unroll
      for (int j = 0; j < 4; ++j) {
        const int slot = m * 4 + j;
        const int lrow = lrl[slot];
        const int rrel = m * 16 + lg * 4 + j;
        const float enthr = en[slot] + 60.f;   // stale-safe (threshold only drops)
        #pragma unroll
        for (int n = 0; n < 4; ++n) {
          const float sv = acc[m][n][j];
          const bool eq = (lcl[n] == lrow);
          // negative log2-logit: G2*(s^2 - 1/16), left branch clamps to 0
          float xn = fmaf(sv * sv, G2, NEG_C);
          xn = (sv > -0.25f) ? xn : 0.f;
          xn = eq ? (3.f * SENT) : xn;         // mask same-label (incl. diagonal)
          if (__builtin_expect(__any(xn > enthr), 0)) {
            // never taken for sane data (needs |s| > 0.6); exact fallback
            const bool r = xn > en[slot] + 60.f;
            float rs = sn[slot] * fexp2(en[slot] - xn) + 1.f;
            float ad = fexp2(xn - en[slot]);
            sn[slot] = r ? rs : (sn[slot] + ad);
            en[slot] = r ? xn : en[slot];
          } else {
            sn[slot] += fexp2(xn - en[slot]);  // hot path: sub+exp2+add
          }
          if (__any(eq)) {                     // positives are rare (~12% of waves)
            const bool isp = eq && (rrel != cgd[n]);
            const float t1 = 1.25f - sv;
            float xp = G2 * fmaxf(t1, 0.f) * (t1 - 0.5f);
            xp = isp ? xp : (3.f * SENT);
            const bool r = xp > ep[slot] + 60.f;   // defer-max: rescale on big jump
            float rs = sp[slot] * fexp2(ep[slot] - xp) + 1.f;
            float ad = fexp2(xp - ep[slot]);
            sp[slot] = r ? rs : (sp[slot] + ad);
            ep[slot] = r ? xp : ep[slot];
            np[slot] += isp ? 1 : 0;
          }
        }
      }
    }
    __syncthreads();   // staged B landed (vmcnt drained at barrier)
  }

  // ---- reduce the 16 lanes sharing each row (xor over lr_)
  #pragma unroll
  for (int q = 0; q < 16; ++q) {
    #pragma unroll
    for (int off = 1; off < 16; off <<= 1) {
      float m2 = __shfl_xor(ep[q], off), s2 = __shfl_xor(sp[q], off);
      lse_merge(ep[q], sp[q], m2, s2);
      m2 = __shfl_xor(en[q], off); s2 = __shfl_xor(sn[q], off);
      lse_merge(en[q], sn[q], m2, s2);
      np[q] += __shfl_xor(np[q], off);
    }
  }

  // ---- merge the two column-half waves (wn=0,1) that share each row
  __syncthreads();                       // all LDS reads of A/B done
  float* S = (float*)A_lds;              // 2 * 64 rows * 5 floats
  if (wn == 1 && lr_ == 0) {
    #pragma unroll
    for (int m = 0; m < 4; ++m)
      #pragma unroll
      for (int j = 0; j < 4; ++j) {
        const int q = m * 4 + j;
        const int r = m * 16 + lg * 4 + j;
        float* p = S + (size_t)(wm * 64 + r) * 5;
        p[0] = ep[q]; p[1] = sp[q]; p[2] = en[q]; p[3] = sn[q]; p[4] = (float)np[q];
      }
  }
  __syncthreads();
  if (wn == 0 && lr_ == 0) {
    #pragma unroll
    for (int m = 0; m < 4; ++m)
      #pragma unroll
      for (int j = 0; j < 4; ++j) {
        const int q = m * 4 + j;
        const int r = m * 16 + lg * 4 + j;
        const float* p = S + (size_t)(wm * 64 + r) * 5;
        lse_merge(ep[q], sp[q], p[0], p[1]);
        lse_merge(en[q], sn[q], p[2], p[3]);
        np[q] += (int)p[4];
        const int row = row0 + wm * 64 + r;
        float* o = &part[((size_t)row * CSPLIT + cs) * PART_STRIDE];
        o[0] = ep[q]; o[1] = sp[q]; o[2] = en[q]; o[3] = sn[q]; o[4] = (float)np[q];
      }
  }
}

// ---- merge column-split partials per row, softplus, block-reduce ----------
__global__ void k_rows(const float* __restrict__ part, float* __restrict__ bsum) {
  const float LN2F = 0.6931471805599453f;
  const int row = blockIdx.x * 256 + threadIdx.x;
  float mp = -INFINITY, sp = 0.f, mn = -INFINITY, sn = 0.f, npf = 0.f;
  #pragma unroll
  for (int c = 0; c < CSPLIT; ++c) {
    const float* p = &part[((size_t)row * CSPLIT + c) * PART_STRIDE];
    lse_merge(mp, sp, p[0], p[1]);
    lse_merge(mn, sn, p[2], p[3]);
    npf += p[4];
  }
  const int npi = (int)(npf + 0.5f);
  const bool valid = (npi > 0) && (npi < NB - 1);
  float val = 0.f;
  if (valid) {
    float lp  = LN2F * (mp + log2f(sp));
    float lnn = LN2F * (mn + log2f(sn));
    float x = lp + lnn;
    val = fmaxf(x, 0.f) + log1pf(expf(-fabsf(x)));  // stable softplus
  }
  float cnt = valid ? 1.f : 0.f;
  val = wave_sum_f(val);
  cnt = wave_sum_f(cnt);
  __shared__ float svals[4], scnts[4];
  const int l = threadIdx.x & 63, w = threadIdx.x >> 6;
  if (l == 0) { svals[w] = val; scnts[w] = cnt; }
  __syncthreads();
  if (threadIdx.x == 0) {
    bsum[blockIdx.x * 2 + 0] = svals[0] + svals[1] + svals[2] + svals[3];
    bsum[blockIdx.x * 2 + 1] = scnts[0] + scnts[1] + scnts[2] + scnts[3];
  }
}

__global__ void k_final(const float* __restrict__ bsum, float* __restrict__ out) {
  const int t = threadIdx.x;
  float s = 0.f, c = 0.f;
  if (t < 32) { s = bsum[t * 2]; c = bsum[t * 2 + 1]; }
  s = wave_sum_f(s);
  c = wave_sum_f(c);
  if (t == 0) out[0] = s / fmaxf(c, 1.f);
}

extern "C" void kernel_launch(void* const* d_in, const int* in_sizes, int n_in,
                              void* d_out, int out_size, void* d_ws, size_t ws_size,
                              hipStream_t stream) {
  const float* emb = (const float*)d_in[0];
  const int* labels = (const int*)d_in[1];
  float* out = (float*)d_out;
  char* ws = (char*)d_ws;

  float* part = (float*)ws;                        // 8192*8*6*4 = 1,572,864 B
  float* bsum = (float*)(ws + 1572864);            // 256 B
  u16*   ebf  = (u16*)(ws + 2097152);              // 2 MB bf16 normalized embeddings

  k_prep<<<NB / 4, 256, 0, stream>>>(emb, ebf);
  k_main<<<(NB / BT) * CSPLIT, 256, 0, stream>>>(ebf, labels, part);
  k_rows<<<NB / 256, 256, 0, stream>>>(part, bsum);
  k_final<<<1, 64, 0, stream>>>(bsum, out);
}

// Round 5
// 86.359 us; speedup vs baseline: 4.0756x; 1.3669x over previous
//
#include <hip/hip_runtime.h>
#include <math.h>

#define NB 8192
#define ND 128
#define BT 128       // tile edge
#define CSPLIT 8     // column splits (blocks per row-tile)
#define CTILES 8     // col tiles per block: 8*128 = 1024 cols
#define NLAB 512
#define MAXM 64      // max members per label handled (data: ~Poisson(16))
#define NCHUNK 16
#define CHUNK 512
#define PERCHUNK 16

typedef unsigned short u16;
typedef unsigned int u32;
typedef __attribute__((ext_vector_type(8))) short bf16x8;
typedef __attribute__((ext_vector_type(4))) float f32x4;

#define G2 369.3299304675746f         // gamma * log2(e)
#define NEG_C (-23.083120654223414f)  // -G2/16
#define SENT (-1e30f)
#define LN2F 0.6931471805599453f

static __device__ __forceinline__ void gload16(const void* g, void* l) {
  __builtin_amdgcn_global_load_lds(
      (const __attribute__((address_space(1))) u32*)g,
      (__attribute__((address_space(3))) u32*)l, 16, 0, 0);
}

static __device__ __forceinline__ float fexp2(float x) {
  return __builtin_amdgcn_exp2f(x);
}

static __device__ __forceinline__ u16 f2bf(float f) {
  u32 u = __float_as_uint(f);
  u32 r = (u + 0x7FFF + ((u >> 16) & 1)) >> 16;   // RNE
  return (u16)r;
}

static __device__ __forceinline__ float wave_sum_f(float v) {
  #pragma unroll
  for (int off = 1; off < 64; off <<= 1) v += __shfl_xor(v, off);
  return v;
}

// ---- normalize rows + cast to bf16 ----------------------------------------
__global__ void k_prep(const float* __restrict__ emb, u16* __restrict__ e) {
  const int l = threadIdx.x & 63;
  const int w = threadIdx.x >> 6;
  const int row = blockIdx.x * 4 + w;
  const float2 v = reinterpret_cast<const float2*>(emb)[(size_t)row * 64 + l];
  float ss = wave_sum_f(v.x * v.x + v.y * v.y);
  const float inv = 1.0f / fmaxf(sqrtf(ss), 1e-12f);
  ushort2 o;
  o.x = f2bf(v.x * inv);
  o.y = f2bf(v.y * inv);
  reinterpret_cast<ushort2*>(e)[(size_t)row * 64 + l] = o;
}

// ---- deterministic per-chunk member lists (no atomics) --------------------
__global__ __launch_bounds__(512) void k_lists(const int* __restrict__ labels,
                                               int* __restrict__ ccount,
                                               int* __restrict__ cmem) {
  __shared__ int lab_lds[CHUNK];
  const int t = threadIdx.x;           // owns label t (labels are in [0,512))
  const int b = blockIdx.x;
  lab_lds[t] = labels[b * CHUNK + t];
  __syncthreads();
  int cnt = 0;
  for (int i = 0; i < CHUNK; ++i) {
    const int lab = lab_lds[i];        // broadcast read
    if (lab == t) {
      if (cnt < PERCHUNK) cmem[(b * NLAB + t) * PERCHUNK + cnt] = b * CHUNK + i;
      ++cnt;
    }
  }
  ccount[b * NLAB + t] = cnt;
}

// ---- MFMA sim tiles + label-free branch-free negative accumulation --------
__global__ __launch_bounds__(256, 2) void k_main(const u16* __restrict__ e,
                                                 float* __restrict__ part) {
  __shared__ char A_lds[BT * 256];     // 32 KB
  __shared__ char B_lds[BT * 256];     // 32 KB

  const int tid = threadIdx.x;
  const int l = tid & 63;
  const int w = tid >> 6;
  const int lr_ = l & 15;
  const int lg = l >> 4;
  const int wm = w >> 1, wn = w & 1;   // wave -> 64x64 quadrant
  const int rt = blockIdx.x >> 3;
  const int cs = blockIdx.x & 7;
  const int row0 = rt * BT;
  const int csbase = cs * (CTILES * BT);

  // stage A tile once; swizzled SOURCE + linear LDS dest (rule 21)
  #pragma unroll
  for (int i = 0; i < 8; ++i) {
    const int rr = w * 32 + i * 4 + lg;
    const int srcslot = lr_ ^ (rr & 15);
    gload16(e + (size_t)(row0 + rr) * ND + srcslot * 8, A_lds + w * 8192 + i * 1024);
  }
  // stage B tile 0
  #pragma unroll
  for (int i = 0; i < 8; ++i) {
    const int rr = w * 32 + i * 4 + lg;
    const int srcslot = lr_ ^ (rr & 15);
    gload16(e + (size_t)(csbase + rr) * ND + srcslot * 8, B_lds + w * 8192 + i * 1024);
  }

  float sn[16];
  #pragma unroll
  for (int q = 0; q < 16; ++q) sn[q] = 0.f;

  __syncthreads();

  for (int it = 0; it < CTILES; ++it) {
    const int colg0 = csbase + it * BT;

    f32x4 acc[4][4];
    #pragma unroll
    for (int m = 0; m < 4; ++m)
      #pragma unroll
      for (int n = 0; n < 4; ++n)
        #pragma unroll
        for (int q = 0; q < 4; ++q) acc[m][n][q] = 0.f;

    #pragma unroll
    for (int ks = 0; ks < 4; ++ks) {
      const int kslot = (ks * 4 + lg) ^ lr_;   // read-side swizzle
      bf16x8 af[4], bfr[4];
      #pragma unroll
      for (int m = 0; m < 4; ++m)
        af[m] = *(const bf16x8*)(A_lds + (wm * 64 + m * 16 + lr_) * 256 + kslot * 16);
      #pragma unroll
      for (int n = 0; n < 4; ++n)
        bfr[n] = *(const bf16x8*)(B_lds + (wn * 64 + n * 16 + lr_) * 256 + kslot * 16);
      #pragma unroll
      for (int m = 0; m < 4; ++m)
        #pragma unroll
        for (int n = 0; n < 4; ++n)
          acc[m][n] = __builtin_amdgcn_mfma_f32_16x16x32_bf16(af[m], bfr[n], acc[m][n], 0, 0, 0);
    }

    __syncthreads();   // all waves finished reading B

    if (it + 1 < CTILES) {   // issue next B tile; lands during epilogue
      const int colg1 = csbase + (it + 1) * BT;
      #pragma unroll
      for (int i = 0; i < 8; ++i) {
        const int rr = w * 32 + i * 4 + lg;
        const int srcslot = lr_ ^ (rr & 15);
        gload16(e + (size_t)(colg1 + rr) * ND + srcslot * 8, B_lds + w * 8192 + i * 1024);
      }
    }

    // branch-free epilogue: sum exp2(neg-logit) over ALL elements; the only
    // exception is the true diagonal (index-masked, wave-uniform branch).
    const bool dwave = (colg0 + wn * 64) == (row0 + wm * 64);
    #pragma unroll
    for (int m = 0; m < 4; ++m) {
      #pragma unroll
      for (int n = 0; n < 4; ++n) {
        if (dwave && m == n) {
          #pragma unroll
          for (int j = 0; j < 4; ++j) {
            const float sv = acc[m][n][j];
            float xn = fmaf(sv * sv, G2, NEG_C);
            xn = (sv > -0.25f) ? xn : 0.f;
            xn = (lr_ == lg * 4 + j) ? SENT : xn;   // exp2(SENT)=0: drop diagonal
            sn[m * 4 + j] += fexp2(xn);
          }
        } else {
          #pragma unroll
          for (int j = 0; j < 4; ++j) {
            const float sv = acc[m][n][j];
            float xn = fmaf(sv * sv, G2, NEG_C);
            xn = (sv > -0.25f) ? xn : 0.f;
            sn[m * 4 + j] += fexp2(xn);
          }
        }
      }
    }
    __syncthreads();   // staged B landed
  }

  // reduce over the 16 columns handled by the lr_ lanes
  #pragma unroll
  for (int q = 0; q < 16; ++q) {
    #pragma unroll
    for (int off = 1; off < 16; off <<= 1) sn[q] += __shfl_xor(sn[q], off);
  }
  if (lr_ == 0) {
    #pragma unroll
    for (int m = 0; m < 4; ++m)
      #pragma unroll
      for (int j = 0; j < 4; ++j) {
        const int row = row0 + wm * 64 + m * 16 + lg * 4 + j;
        part[(size_t)row * 16 + cs * 2 + wn] = sn[m * 4 + j];
      }
  }
}

// ---- per-label pass: positives LSE + same-label negative correction -------
// Recomputes pairwise sims BIT-IDENTICALLY to k_main (same MFMA, same K=32
// chunk order, same fragment layout) so the correction subtraction is exact.
__global__ __launch_bounds__(256) void k_pos(const u16* __restrict__ e,
                                             const int* __restrict__ ccount,
                                             const int* __restrict__ cmem,
                                             float* __restrict__ poscorr) {
  __shared__ int memL[4][MAXM];
  const int tid = threadIdx.x;
  const int l = tid & 63;
  const int w = tid >> 6;
  const int L = blockIdx.x * 4 + w;    // one wave per label
  const int lr_ = l & 15;
  const int lg = l >> 4;

  // inline deterministic concat of the 16 chunk lists
  int c = 0;
  for (int b = 0; b < NCHUNK; ++b) {
    const int cn = ccount[b * NLAB + L];
    for (int q = 0; q < cn; ++q) {
      const int idx = cmem[(b * NLAB + L) * PERCHUNK + q];
      if (l == 0 && c < MAXM) memL[w][c] = idx;
      ++c;
    }
  }
  if (c > MAXM) c = MAXM;

  const int nt = (c + 15) >> 4;
  for (int rb = 0; rb < nt; ++rb) {
    const int ri = rb * 16 + lr_;
    bf16x8 af[4];
    if (ri < c) {
      const u16* src = e + (size_t)memL[w][ri] * ND;
      #pragma unroll
      for (int ks = 0; ks < 4; ++ks)
        af[ks] = *(const bf16x8*)(src + ks * 32 + lg * 8);
    } else {
      #pragma unroll
      for (int ks = 0; ks < 4; ++ks) af[ks] = (bf16x8)0;
    }
    float corr[4], mp[4], sp[4];
    #pragma unroll
    for (int r = 0; r < 4; ++r) { corr[r] = 0.f; mp[r] = SENT; sp[r] = 0.f; }

    for (int cb = 0; cb < nt; ++cb) {
      const int ci = cb * 16 + lr_;
      bf16x8 bfr[4];
      if (ci < c) {
        const u16* src = e + (size_t)memL[w][ci] * ND;
        #pragma unroll
        for (int ks = 0; ks < 4; ++ks)
          bfr[ks] = *(const bf16x8*)(src + ks * 32 + lg * 8);
      } else {
        #pragma unroll
        for (int ks = 0; ks < 4; ++ks) bfr[ks] = (bf16x8)0;
      }
      f32x4 acc;
      #pragma unroll
      for (int r = 0; r < 4; ++r) acc[r] = 0.f;
      #pragma unroll
      for (int ks = 0; ks < 4; ++ks)
        acc = __builtin_amdgcn_mfma_f32_16x16x32_bf16(af[ks], bfr[ks], acc, 0, 0, 0);

      #pragma unroll
      for (int r = 0; r < 4; ++r) {
        const int R = rb * 16 + lg * 4 + r;
        const int Cj = cb * 16 + lr_;
        const bool ok = (R < c) && (Cj < c) && (R != Cj);
        const float sv = acc[r];
        float xn = fmaf(sv * sv, G2, NEG_C);
        xn = (sv > -0.25f) ? xn : 0.f;
        corr[r] += ok ? fexp2(xn) : 0.f;
        if (ok) {
          const float t1 = 1.25f - sv;
          const float xp = G2 * fmaxf(t1, 0.f) * (t1 - 0.5f);
          if (xp > mp[r]) { sp[r] = sp[r] * fexp2(mp[r] - xp) + 1.f; mp[r] = xp; }
          else sp[r] += fexp2(xp - mp[r]);
        }
      }
    }
    // reduce over the 16 column-lanes
    #pragma unroll
    for (int r = 0; r < 4; ++r) {
      #pragma unroll
      for (int off = 1; off < 16; off <<= 1) {
        corr[r] += __shfl_xor(corr[r], off);
        const float m2 = __shfl_xor(mp[r], off), s2 = __shfl_xor(sp[r], off);
        const float M = fmaxf(mp[r], m2);
        const float t1 = sp[r] * fexp2(mp[r] - M);  // finite sentinel: exp2(-1e30)=0
        const float t2 = s2 * fexp2(m2 - M);
        mp[r] = M; sp[r] = t1 + t2;
      }
    }
    if (lr_ == 0) {
      #pragma unroll
      for (int r = 0; r < 4; ++r) {
        const int R = rb * 16 + lg * 4 + r;
        if (R < c) {
          float* o = poscorr + (size_t)memL[w][R] * 4;
          o[0] = mp[r]; o[1] = sp[r]; o[2] = corr[r]; o[3] = (float)(c - 1);
        }
      }
    }
  }
}

// ---- per-row finish: subtract correction, softplus, reduce ----------------
__global__ void k_rows(const float* __restrict__ part,
                       const float* __restrict__ poscorr,
                       float* __restrict__ bsum) {
  const int row = blockIdx.x * 256 + threadIdx.x;
  float sn = 0.f;
  #pragma unroll
  for (int q = 0; q < 16; ++q) sn += part[(size_t)row * 16 + q];
  const float4 pc = *reinterpret_cast<const float4*>(poscorr + (size_t)row * 4);
  const int npi = (int)(pc.w + 0.5f);
  const bool valid = (npi > 0) && (npi < NB - 1);
  float val = 0.f;
  if (valid) {
    const float snn = fmaxf(sn - pc.z, 1e-30f);
    const float lp = LN2F * (pc.x + log2f(pc.y));
    const float ln_ = LN2F * log2f(snn);
    const float x = lp + ln_;
    val = fmaxf(x, 0.f) + log1pf(expf(-fabsf(x)));  // stable softplus
  }
  float cnt = valid ? 1.f : 0.f;
  val = wave_sum_f(val);
  cnt = wave_sum_f(cnt);
  __shared__ float svals[4], scnts[4];
  const int l = threadIdx.x & 63, w = threadIdx.x >> 6;
  if (l == 0) { svals[w] = val; scnts[w] = cnt; }
  __syncthreads();
  if (threadIdx.x == 0) {
    bsum[blockIdx.x * 2 + 0] = svals[0] + svals[1] + svals[2] + svals[3];
    bsum[blockIdx.x * 2 + 1] = scnts[0] + scnts[1] + scnts[2] + scnts[3];
  }
}

__global__ void k_final(const float* __restrict__ bsum, float* __restrict__ out) {
  const int t = threadIdx.x;
  float s = 0.f, c = 0.f;
  if (t < 32) { s = bsum[t * 2]; c = bsum[t * 2 + 1]; }
  s = wave_sum_f(s);
  c = wave_sum_f(c);
  if (t == 0) out[0] = s / fmaxf(c, 1.f);
}

extern "C" void kernel_launch(void* const* d_in, const int* in_sizes, int n_in,
                              void* d_out, int out_size, void* d_ws, size_t ws_size,
                              hipStream_t stream) {
  const float* emb = (const float*)d_in[0];
  const int* labels = (const int*)d_in[1];
  float* out = (float*)d_out;
  char* ws = (char*)d_ws;

  float* part    = (float*)(ws + 0);         // 8192*16*4      = 524288
  float* poscorr = (float*)(ws + 524288);    // 8192*4*4       = 131072
  u16*   ebf     = (u16*)  (ws + 655360);    // 8192*128*2     = 2097152
  int*   ccount  = (int*)  (ws + 2752512);   // 16*512*4       = 32768
  int*   cmem    = (int*)  (ws + 2785280);   // 16*512*16*4    = 524288
  float* bsum    = (float*)(ws + 3309568);   // 64*4

  k_prep <<<NB / 4, 256, 0, stream>>>(emb, ebf);
  k_lists<<<NCHUNK, 512, 0, stream>>>(labels, ccount, cmem);
  k_main <<<(NB / BT) * CSPLIT, 256, 0, stream>>>(ebf, part);
  k_pos  <<<NLAB / 4, 256, 0, stream>>>(ebf, ccount, cmem, poscorr);
  k_rows <<<NB / 256, 256, 0, stream>>>(part, poscorr, bsum);
  k_final<<<1, 64, 0, stream>>>(bsum, out);
}

// Round 6
// 62.303 us; speedup vs baseline: 5.6492x; 1.3861x over previous
//
#include <hip/hip_runtime.h>
#include <math.h>

#define NB 8192
#define ND 128
#define BT 128       // rows per block
#define CB 64        // cols per tile
#define CSPLIT 16    // column splits (blocks per row-tile)
#define CTILES 8     // col tiles per block: 8*64 = 512 cols
#define NLAB 512
#define MAXM 64
#define NCHUNK 16
#define CHUNK 512
#define PERCHUNK 16

typedef unsigned short u16;
typedef unsigned int u32;
typedef __attribute__((ext_vector_type(8))) short bf16x8;
typedef __attribute__((ext_vector_type(4))) float f32x4;

#define G2 369.3299304675746f         // gamma * log2(e)
#define NEG_C (-23.083120654223414f)  // -G2/16
#define SENT (-1e30f)
#define LN2F 0.6931471805599453f

static __device__ __forceinline__ void gload16(const void* g, void* l) {
  __builtin_amdgcn_global_load_lds(
      (const __attribute__((address_space(1))) u32*)g,
      (__attribute__((address_space(3))) u32*)l, 16, 0, 0);
}

static __device__ __forceinline__ float fexp2(float x) {
  return __builtin_amdgcn_exp2f(x);
}

static __device__ __forceinline__ u16 f2bf(float f) {
  u32 u = __float_as_uint(f);
  u32 r = (u + 0x7FFF + ((u >> 16) & 1)) >> 16;   // RNE
  return (u16)r;
}

static __device__ __forceinline__ float wave_sum_f(float v) {
  #pragma unroll
  for (int off = 1; off < 64; off <<= 1) v += __shfl_xor(v, off);
  return v;
}

// ---- fused: normalize+cast rows (blocks 0..1023) | member lists (1024..1039)
__global__ __launch_bounds__(512) void k_prep_lists(const float* __restrict__ emb,
                                                    const int* __restrict__ labels,
                                                    u16* __restrict__ e,
                                                    int* __restrict__ ccount,
                                                    int* __restrict__ cmem) {
  __shared__ __align__(16) int lab_lds[CHUNK];
  if (blockIdx.x < 1024) {
    const int l = threadIdx.x & 63;
    const int w = threadIdx.x >> 6;
    const int row = blockIdx.x * 8 + w;
    const float2 v = reinterpret_cast<const float2*>(emb)[(size_t)row * 64 + l];
    float ss = wave_sum_f(v.x * v.x + v.y * v.y);
    const float inv = 1.0f / fmaxf(sqrtf(ss), 1e-12f);
    ushort2 o;
    o.x = f2bf(v.x * inv);
    o.y = f2bf(v.y * inv);
    reinterpret_cast<ushort2*>(e)[(size_t)row * 64 + l] = o;
  } else {
    const int t = threadIdx.x;         // owns label t (labels in [0,512))
    const int b = blockIdx.x - 1024;
    lab_lds[t] = labels[b * CHUNK + t];
    __syncthreads();
    int cnt = 0;
    #define CHK(LAB, IDX)                                                   \
      if ((LAB) == t) {                                                     \
        if (cnt < PERCHUNK) cmem[(b * NLAB + t) * PERCHUNK + cnt] = b * CHUNK + (IDX); \
        ++cnt;                                                              \
      }
    for (int i = 0; i < CHUNK; i += 8) {   // 8-wide: pipelined LDS reads
      const int4 a = *(const int4*)&lab_lds[i];
      const int4 c4 = *(const int4*)&lab_lds[i + 4];
      CHK(a.x, i + 0) CHK(a.y, i + 1) CHK(a.z, i + 2) CHK(a.w, i + 3)
      CHK(c4.x, i + 4) CHK(c4.y, i + 5) CHK(c4.z, i + 6) CHK(c4.w, i + 7)
    }
    #undef CHK
    ccount[b * NLAB + t] = cnt;
  }
}

// ---- MFMA sim tiles + branch-free fixed-base negative accumulation --------
// A fragments in registers (global loads, bit-identical to k_pos's), B in LDS.
__global__ __launch_bounds__(256, 4) void k_main(const u16* __restrict__ e,
                                                 float* __restrict__ part) {
  __shared__ char B_lds[CB * 256];     // 16 KB
  const int tid = threadIdx.x;
  const int l = tid & 63;
  const int w = tid >> 6;              // wave 0..3 -> rows w*32..+32
  const int lr_ = l & 15;
  const int lg = l >> 4;
  const int rt = blockIdx.x >> 4;
  const int cs = blockIdx.x & 15;
  const int row0 = rt * BT;
  const int csbase = cs * (CTILES * CB);

  // A fragments: af[m][ks] for rows row0 + w*32 + m*16 + lr_
  bf16x8 af[2][4];
  #pragma unroll
  for (int m = 0; m < 2; ++m)
    #pragma unroll
    for (int ks = 0; ks < 4; ++ks)
      af[m][ks] = *(const bf16x8*)(e + (size_t)(row0 + w * 32 + m * 16 + lr_) * ND +
                                   ks * 32 + lg * 8);

  // stage B tile 0 (swizzled source, linear LDS dest)
  #pragma unroll
  for (int i = 0; i < 4; ++i) {
    const int rr = w * 16 + i * 4 + lg;
    gload16(e + (size_t)(csbase + rr) * ND + (lr_ ^ (rr & 15)) * 8,
            B_lds + w * 4096 + i * 1024);
  }

  float sn[8];
  #pragma unroll
  for (int q = 0; q < 8; ++q) sn[q] = 0.f;

  __syncthreads();   // B0 landed (barrier drains vmcnt)

  for (int it = 0; it < CTILES; ++it) {
    const int colg0 = csbase + it * CB;

    f32x4 acc[2][4];
    #pragma unroll
    for (int m = 0; m < 2; ++m)
      #pragma unroll
      for (int n = 0; n < 4; ++n)
        #pragma unroll
        for (int q = 0; q < 4; ++q) acc[m][n][q] = 0.f;

    #pragma unroll
    for (int ks = 0; ks < 4; ++ks) {
      const int kslot = (ks * 4 + lg) ^ lr_;   // read-side swizzle
      bf16x8 bfr[4];
      #pragma unroll
      for (int n = 0; n < 4; ++n)
        bfr[n] = *(const bf16x8*)(B_lds + (n * 16 + lr_) * 256 + kslot * 16);
      #pragma unroll
      for (int m = 0; m < 2; ++m)
        #pragma unroll
        for (int n = 0; n < 4; ++n)
          acc[m][n] = __builtin_amdgcn_mfma_f32_16x16x32_bf16(af[m][ks], bfr[n],
                                                              acc[m][n], 0, 0, 0);
    }

    __syncthreads();   // all waves finished reading B

    if (it + 1 < CTILES) {   // prefetch next B; lands during epilogue
      const int colg1 = colg0 + CB;
      #pragma unroll
      for (int i = 0; i < 4; ++i) {
        const int rr = w * 16 + i * 4 + lg;
        gload16(e + (size_t)(colg1 + rr) * ND + (lr_ ^ (rr & 15)) * 8,
                B_lds + w * 4096 + i * 1024);
      }
    }

    // branch-free epilogue; diagonal sub-tiles masked by index (uniform branch)
    #pragma unroll
    for (int m = 0; m < 2; ++m) {
      #pragma unroll
      for (int n = 0; n < 4; ++n) {
        const bool dmn = (row0 + w * 32 + m * 16) == (colg0 + n * 16);
        if (dmn) {
          #pragma unroll
          for (int j = 0; j < 4; ++j) {
            const float sv = acc[m][n][j];
            float xn = fmaf(sv * sv, G2, NEG_C);
            xn = (sv > -0.25f) ? xn : 0.f;
            xn = (lr_ == lg * 4 + j) ? SENT : xn;   // exp2(SENT)=0: drop diagonal
            sn[m * 4 + j] += fexp2(xn);
          }
        } else {
          #pragma unroll
          for (int j = 0; j < 4; ++j) {
            const float sv = acc[m][n][j];
            float xn = fmaf(sv * sv, G2, NEG_C);
            xn = (sv > -0.25f) ? xn : 0.f;
            sn[m * 4 + j] += fexp2(xn);
          }
        }
      }
    }
    __syncthreads();   // prefetched B landed
  }

  // reduce over the 16 column-lanes; rows are wave-private -> direct write
  #pragma unroll
  for (int q = 0; q < 8; ++q) {
    #pragma unroll
    for (int off = 1; off < 16; off <<= 1) sn[q] += __shfl_xor(sn[q], off);
  }
  if (lr_ == 0) {
    #pragma unroll
    for (int m = 0; m < 2; ++m)
      #pragma unroll
      for (int j = 0; j < 4; ++j) {
        const int row = row0 + w * 32 + m * 16 + lg * 4 + j;
        part[(size_t)row * CSPLIT + cs] = sn[m * 4 + j];
      }
  }
}

// ---- per-label pass: positives LSE + same-label negative correction -------
__global__ __launch_bounds__(256) void k_pos(const u16* __restrict__ e,
                                             const int* __restrict__ ccount,
                                             const int* __restrict__ cmem,
                                             float* __restrict__ poscorr) {
  __shared__ int memL[4][MAXM];
  const int tid = threadIdx.x;
  const int l = tid & 63;
  const int w = tid >> 6;
  const int L = blockIdx.x * 4 + w;    // one wave per label
  const int lr_ = l & 15;
  const int lg = l >> 4;

  // parallel gather: 16 lanes load chunk counts, prefix-scan, parallel copy
  int cnt_l = 0;
  if (l < NCHUNK) cnt_l = min(ccount[l * NLAB + L], PERCHUNK);
  int pref = cnt_l;
  #pragma unroll
  for (int s = 1; s < 16; s <<= 1) {
    const int t = __shfl_up(pref, s);
    if (l >= s) pref += t;             // lanes >=16 compute garbage; unused
  }
  int c = __shfl(pref, 15);
  const int base = pref - cnt_l;
  if (l < NCHUNK) {
    for (int q = 0; q < cnt_l; ++q) {
      const int idx = cmem[(l * NLAB + L) * PERCHUNK + q];
      if (base + q < MAXM) memL[w][base + q] = idx;
    }
  }
  if (c > MAXM) c = MAXM;

  const int nt = (c + 15) >> 4;
  for (int rb = 0; rb < nt; ++rb) {
    const int ri = rb * 16 + lr_;
    bf16x8 af[4];
    if (ri < c) {
      const u16* src = e + (size_t)memL[w][ri] * ND;
      #pragma unroll
      for (int ks = 0; ks < 4; ++ks)
        af[ks] = *(const bf16x8*)(src + ks * 32 + lg * 8);
    } else {
      #pragma unroll
      for (int ks = 0; ks < 4; ++ks) af[ks] = (bf16x8)0;
    }
    float corr[4], mp[4], sp[4];
    #pragma unroll
    for (int r = 0; r < 4; ++r) { corr[r] = 0.f; mp[r] = SENT; sp[r] = 0.f; }

    for (int cb = 0; cb < nt; ++cb) {
      const int ci = cb * 16 + lr_;
      bf16x8 bfr[4];
      if (ci < c) {
        const u16* src = e + (size_t)memL[w][ci] * ND;
        #pragma unroll
        for (int ks = 0; ks < 4; ++ks)
          bfr[ks] = *(const bf16x8*)(src + ks * 32 + lg * 8);
      } else {
        #pragma unroll
        for (int ks = 0; ks < 4; ++ks) bfr[ks] = (bf16x8)0;
      }
      f32x4 acc;
      #pragma unroll
      for (int r = 0; r < 4; ++r) acc[r] = 0.f;
      #pragma unroll
      for (int ks = 0; ks < 4; ++ks)
        acc = __builtin_amdgcn_mfma_f32_16x16x32_bf16(af[ks], bfr[ks], acc, 0, 0, 0);

      #pragma unroll
      for (int r = 0; r < 4; ++r) {
        const int R = rb * 16 + lg * 4 + r;
        const int Cj = cb * 16 + lr_;
        const bool ok = (R < c) && (Cj < c) && (R != Cj);
        const float sv = acc[r];
        float xn = fmaf(sv * sv, G2, NEG_C);
        xn = (sv > -0.25f) ? xn : 0.f;
        corr[r] += ok ? fexp2(xn) : 0.f;
        if (ok) {
          const float t1 = 1.25f - sv;
          const float xp = G2 * fmaxf(t1, 0.f) * (t1 - 0.5f);
          if (xp > mp[r]) { sp[r] = sp[r] * fexp2(mp[r] - xp) + 1.f; mp[r] = xp; }
          else sp[r] += fexp2(xp - mp[r]);
        }
      }
    }
    // reduce over the 16 column-lanes
    #pragma unroll
    for (int r = 0; r < 4; ++r) {
      #pragma unroll
      for (int off = 1; off < 16; off <<= 1) {
        corr[r] += __shfl_xor(corr[r], off);
        const float m2 = __shfl_xor(mp[r], off), s2 = __shfl_xor(sp[r], off);
        const float M = fmaxf(mp[r], m2);
        const float t1 = sp[r] * fexp2(mp[r] - M);  // exp2(-1e30)=0 handles empties
        const float t2 = s2 * fexp2(m2 - M);
        mp[r] = M; sp[r] = t1 + t2;
      }
    }
    if (lr_ == 0) {
      #pragma unroll
      for (int r = 0; r < 4; ++r) {
        const int R = rb * 16 + lg * 4 + r;
        if (R < c) {
          float* o = poscorr + (size_t)memL[w][R] * 4;
          o[0] = mp[r]; o[1] = sp[r]; o[2] = corr[r]; o[3] = (float)(c - 1);
        }
      }
    }
  }
}

// ---- per-row finish: subtract correction, softplus, reduce ----------------
__global__ void k_rows(const float* __restrict__ part,
                       const float* __restrict__ poscorr,
                       float* __restrict__ bsum) {
  const int row = blockIdx.x * 256 + threadIdx.x;
  float sn = 0.f;
  #pragma unroll
  for (int q = 0; q < CSPLIT; ++q) sn += part[(size_t)row * CSPLIT + q];
  const float4 pc = *reinterpret_cast<const float4*>(poscorr + (size_t)row * 4);
  const int npi = (int)(pc.w + 0.5f);
  const bool valid = (npi > 0) && (npi < NB - 1);
  float val = 0.f;
  if (valid) {
    const float snn = fmaxf(sn - pc.z, 1e-30f);
    const float lp = LN2F * (pc.x + log2f(pc.y));
    const float ln_ = LN2F * log2f(snn);
    const float x = lp + ln_;
    val = fmaxf(x, 0.f) + log1pf(expf(-fabsf(x)));  // stable softplus
  }
  float cnt = valid ? 1.f : 0.f;
  val = wave_sum_f(val);
  cnt = wave_sum_f(cnt);
  __shared__ float svals[4], scnts[4];
  const int l = threadIdx.x & 63, w = threadIdx.x >> 6;
  if (l == 0) { svals[w] = val; scnts[w] = cnt; }
  __syncthreads();
  if (threadIdx.x == 0) {
    bsum[blockIdx.x * 2 + 0] = svals[0] + svals[1] + svals[2] + svals[3];
    bsum[blockIdx.x * 2 + 1] = scnts[0] + scnts[1] + scnts[2] + scnts[3];
  }
}

__global__ void k_final(const float* __restrict__ bsum, float* __restrict__ out) {
  const int t = threadIdx.x;
  float s = 0.f, c = 0.f;
  if (t < 32) { s = bsum[t * 2]; c = bsum[t * 2 + 1]; }
  s = wave_sum_f(s);
  c = wave_sum_f(c);
  if (t == 0) out[0] = s / fmaxf(c, 1.f);
}

extern "C" void kernel_launch(void* const* d_in, const int* in_sizes, int n_in,
                              void* d_out, int out_size, void* d_ws, size_t ws_size,
                              hipStream_t stream) {
  const float* emb = (const float*)d_in[0];
  const int* labels = (const int*)d_in[1];
  float* out = (float*)d_out;
  char* ws = (char*)d_ws;

  float* part    = (float*)(ws + 0);         // 8192*16*4      = 524288
  float* poscorr = (float*)(ws + 524288);    // 8192*4*4       = 131072
  u16*   ebf     = (u16*)  (ws + 655360);    // 8192*128*2     = 2097152
  int*   ccount  = (int*)  (ws + 2752512);   // 16*512*4       = 32768
  int*   cmem    = (int*)  (ws + 2785280);   // 16*512*16*4    = 524288
  float* bsum    = (float*)(ws + 3309568);   // 64*4

  k_prep_lists<<<1040, 512, 0, stream>>>(emb, labels, ebf, ccount, cmem);
  k_main <<<(NB / BT) * CSPLIT, 256, 0, stream>>>(ebf, part);
  k_pos  <<<NLAB / 4, 256, 0, stream>>>(ebf, ccount, cmem, poscorr);
  k_rows <<<NB / 256, 256, 0, stream>>>(part, poscorr, bsum);
  k_final<<<1, 64, 0, stream>>>(bsum, out);
}

// Round 7
// 61.310 us; speedup vs baseline: 5.7407x; 1.0162x over previous
//
#include <hip/hip_runtime.h>
#include <math.h>

#define NB 8192
#define ND 128
#define NT 64        // number of 128-row tiles (NB/128)
#define NLAB 512
#define MAXM 64
#define NCHUNK 16
#define CHUNK 512
#define PERCHUNK 16

typedef unsigned short u16;
typedef unsigned int u32;
typedef __attribute__((ext_vector_type(8))) short bf16x8;
typedef __attribute__((ext_vector_type(4))) float f32x4;

#define G2 369.3299304675746f         // gamma * log2(e)
#define NEG_C (-23.083120654223414f)  // -G2/16
#define SENT (-1e30f)
#define LN2F 0.6931471805599453f

static __device__ __forceinline__ void gload16(const void* g, void* l) {
  __builtin_amdgcn_global_load_lds(
      (const __attribute__((address_space(1))) u32*)g,
      (__attribute__((address_space(3))) u32*)l, 16, 0, 0);
}

static __device__ __forceinline__ float fexp2(float x) {
  return __builtin_amdgcn_exp2f(x);
}

static __device__ __forceinline__ u16 f2bf(float f) {
  u32 u = __float_as_uint(f);
  u32 r = (u + 0x7FFF + ((u >> 16) & 1)) >> 16;   // RNE
  return (u16)r;
}

static __device__ __forceinline__ float wave_sum_f(float v) {
  #pragma unroll
  for (int off = 1; off < 64; off <<= 1) v += __shfl_xor(v, off);
  return v;
}

// ---- fused: normalize+cast rows (blocks 0..1023) | member lists (1024..1039)
__global__ __launch_bounds__(512) void k_prep_lists(const float* __restrict__ emb,
                                                    const int* __restrict__ labels,
                                                    u16* __restrict__ e,
                                                    int* __restrict__ ccount,
                                                    int* __restrict__ cmem) {
  __shared__ __align__(16) int lab_lds[CHUNK];
  if (blockIdx.x < 1024) {
    const int l = threadIdx.x & 63;
    const int w = threadIdx.x >> 6;
    const int row = blockIdx.x * 8 + w;
    const float2 v = reinterpret_cast<const float2*>(emb)[(size_t)row * 64 + l];
    float ss = wave_sum_f(v.x * v.x + v.y * v.y);
    const float inv = 1.0f / fmaxf(sqrtf(ss), 1e-12f);
    ushort2 o;
    o.x = f2bf(v.x * inv);
    o.y = f2bf(v.y * inv);
    reinterpret_cast<ushort2*>(e)[(size_t)row * 64 + l] = o;
  } else {
    const int t = threadIdx.x;         // owns label t (labels in [0,512))
    const int b = blockIdx.x - 1024;
    lab_lds[t] = labels[b * CHUNK + t];
    __syncthreads();
    int cnt = 0;
    #define CHK(LAB, IDX)                                                   \
      if ((LAB) == t) {                                                     \
        if (cnt < PERCHUNK) cmem[(b * NLAB + t) * PERCHUNK + cnt] = b * CHUNK + (IDX); \
        ++cnt;                                                              \
      }
    for (int i = 0; i < CHUNK; i += 8) {   // 8-wide: pipelined LDS reads
      const int4 a = *(const int4*)&lab_lds[i];
      const int4 c4 = *(const int4*)&lab_lds[i + 4];
      CHK(a.x, i + 0) CHK(a.y, i + 1) CHK(a.z, i + 2) CHK(a.w, i + 3)
      CHK(c4.x, i + 4) CHK(c4.y, i + 5) CHK(c4.z, i + 6) CHK(c4.w, i + 7)
    }
    #undef CHK
    ccount[b * NLAB + t] = cnt;
  }
}

// ---- upper-triangle MFMA sim tiles; row sums + symmetric column sums ------
// part[row][64]: slot k<ti from col-path of block (k,ti); slot k>=ti from
// row-path of block (ti,k). Every slot written exactly once (deterministic).
__global__ __launch_bounds__(256, 3) void k_main(const u16* __restrict__ e,
                                                 float* __restrict__ part) {
  __shared__ char B_lds[2][64 * 256];  // two 64-col halves, double-buffered
  const int tid = threadIdx.x;
  const int l = tid & 63;
  const int w = tid >> 6;              // wave 0..3 -> rows w*32..+32
  const int lr_ = l & 15;
  const int lg = l >> 4;

  // blockIdx -> (ti, tj) upper triangle; pre(t) = blocks before row t
  const int b = blockIdx.x;
  int ti = (int)((129.0f - sqrtf(16641.0f - 8.0f * (float)b)) * 0.5f);
  if (ti > NT - 1) ti = NT - 1;
  if (ti < 0) ti = 0;
  #define PRE(t) ((t) * NT - ((t) * ((t) - 1)) / 2)
  while (PRE(ti + 1) <= b) ++ti;
  while (PRE(ti) > b) --ti;
  const int tj = ti + (b - PRE(ti));
  #undef PRE
  const int row0 = ti * 128;
  const int col0 = tj * 128;
  const bool diag = (ti == tj);

  // A fragments in registers: rows row0 + w*32 + m*16 + lr_
  bf16x8 af[2][4];
  #pragma unroll
  for (int m = 0; m < 2; ++m)
    #pragma unroll
    for (int ks = 0; ks < 4; ++ks)
      af[m][ks] = *(const bf16x8*)(e + (size_t)(row0 + w * 32 + m * 16 + lr_) * ND +
                                   ks * 32 + lg * 8);

  // stage half 0 (swizzled source, linear LDS dest)
  #pragma unroll
  for (int i = 0; i < 4; ++i) {
    const int rr = w * 16 + i * 4 + lg;
    gload16(e + (size_t)(col0 + rr) * ND + (lr_ ^ (rr & 15)) * 8,
            B_lds[0] + w * 4096 + i * 1024);
  }

  float sn[8], colp[8];
  #pragma unroll
  for (int q = 0; q < 8; ++q) { sn[q] = 0.f; colp[q] = 0.f; }

  __syncthreads();   // half 0 landed

  // stage half 1 now; lands during half-0 compute
  #pragma unroll
  for (int i = 0; i < 4; ++i) {
    const int rr = w * 16 + i * 4 + lg;
    gload16(e + (size_t)(col0 + 64 + rr) * ND + (lr_ ^ (rr & 15)) * 8,
            B_lds[1] + w * 4096 + i * 1024);
  }

  #pragma unroll
  for (int h = 0; h < 2; ++h) {
    f32x4 acc[2][4];
    #pragma unroll
    for (int m = 0; m < 2; ++m)
      #pragma unroll
      for (int n = 0; n < 4; ++n)
        #pragma unroll
        for (int q = 0; q < 4; ++q) acc[m][n][q] = 0.f;

    #pragma unroll
    for (int ks = 0; ks < 4; ++ks) {
      const int kslot = (ks * 4 + lg) ^ lr_;   // read-side swizzle
      bf16x8 bfr[4];
      #pragma unroll
      for (int n = 0; n < 4; ++n)
        bfr[n] = *(const bf16x8*)(B_lds[h] + (n * 16 + lr_) * 256 + kslot * 16);
      #pragma unroll
      for (int m = 0; m < 2; ++m)
        #pragma unroll
        for (int n = 0; n < 4; ++n)
          acc[m][n] = __builtin_amdgcn_mfma_f32_16x16x32_bf16(af[m][ks], bfr[n],
                                                              acc[m][n], 0, 0, 0);
    }

    // epilogue: ev feeds both the row sums and (by symmetry) the column sums
    #pragma unroll
    for (int m = 0; m < 2; ++m) {
      #pragma unroll
      for (int n = 0; n < 4; ++n) {
        const bool dmn = diag && (w * 32 + m * 16 == h * 64 + n * 16);
        float scc = 0.f;
        #pragma unroll
        for (int j = 0; j < 4; ++j) {
          const float sv = acc[m][n][j];
          float xn = fmaf(sv * sv, G2, NEG_C);
          xn = (sv > -0.25f) ? xn : 0.f;
          if (dmn) xn = (lr_ == lg * 4 + j) ? SENT : xn;  // drop true diagonal
          const float ev = fexp2(xn);
          sn[m * 4 + j] += ev;
          scc += ev;
        }
        colp[h * 4 + n] += scc;   // unused for diag blocks (harmless)
      }
    }
    if (h == 0) __syncthreads();   // half 1 landed (barrier drains vmcnt)
  }

  // row sums: reduce over the 16 column-lanes, write slot tj
  #pragma unroll
  for (int q = 0; q < 8; ++q) {
    #pragma unroll
    for (int off = 1; off < 16; off <<= 1) sn[q] += __shfl_xor(sn[q], off);
  }
  if (lr_ == 0) {
    #pragma unroll
    for (int m = 0; m < 2; ++m)
      #pragma unroll
      for (int j = 0; j < 4; ++j) {
        const int row = row0 + w * 32 + m * 16 + lg * 4 + j;
        part[(size_t)row * NT + tj] = sn[m * 4 + j];
      }
  }

  // column sums (skip diagonal blocks): reduce lg groups, cross-wave via LDS
  if (!diag) {
    #pragma unroll
    for (int q = 0; q < 8; ++q) {
      colp[q] += __shfl_xor(colp[q], 16);
      colp[q] += __shfl_xor(colp[q], 32);
    }
    __syncthreads();                     // all MFMA LDS reads done; safe to reuse
    float* colbuf = (float*)B_lds;       // 4 waves * 128 cols
    if (l < 16) {
      #pragma unroll
      for (int q = 0; q < 8; ++q)
        colbuf[w * 128 + (q >> 2) * 64 + (q & 3) * 16 + lr_] = colp[q];
    }
    __syncthreads();
    if (tid < 128) {
      const float cs_ = colbuf[tid] + colbuf[128 + tid] +
                        colbuf[256 + tid] + colbuf[384 + tid];
      part[(size_t)(col0 + tid) * NT + ti] = cs_;
    }
  }
}

// ---- per-label pass: positives LSE + same-label negative correction -------
__global__ __launch_bounds__(256) void k_pos(const u16* __restrict__ e,
                                             const int* __restrict__ ccount,
                                             const int* __restrict__ cmem,
                                             float* __restrict__ poscorr) {
  __shared__ int memL[4][MAXM];
  const int tid = threadIdx.x;
  const int l = tid & 63;
  const int w = tid >> 6;
  const int L = blockIdx.x * 4 + w;    // one wave per label
  const int lr_ = l & 15;
  const int lg = l >> 4;

  // parallel gather: 16 lanes load chunk counts, prefix-scan, parallel copy
  int cnt_l = 0;
  if (l < NCHUNK) cnt_l = min(ccount[l * NLAB + L], PERCHUNK);
  int pref = cnt_l;
  #pragma unroll
  for (int s = 1; s < 16; s <<= 1) {
    const int t = __shfl_up(pref, s);
    if (l >= s) pref += t;             // lanes >=16 compute garbage; unused
  }
  int c = __shfl(pref, 15);
  const int base = pref - cnt_l;
  if (l < NCHUNK) {
    for (int q = 0; q < cnt_l; ++q) {
      const int idx = cmem[(l * NLAB + L) * PERCHUNK + q];
      if (base + q < MAXM) memL[w][base + q] = idx;
    }
  }
  if (c > MAXM) c = MAXM;

  const int nt = (c + 15) >> 4;
  for (int rb = 0; rb < nt; ++rb) {
    const int ri = rb * 16 + lr_;
    bf16x8 af[4];
    if (ri < c) {
      const u16* src = e + (size_t)memL[w][ri] * ND;
      #pragma unroll
      for (int ks = 0; ks < 4; ++ks)
        af[ks] = *(const bf16x8*)(src + ks * 32 + lg * 8);
    } else {
      #pragma unroll
      for (int ks = 0; ks < 4; ++ks) af[ks] = (bf16x8)0;
    }
    float corr[4], mp[4], sp[4];
    #pragma unroll
    for (int r = 0; r < 4; ++r) { corr[r] = 0.f; mp[r] = SENT; sp[r] = 0.f; }

    for (int cb = 0; cb < nt; ++cb) {
      const int ci = cb * 16 + lr_;
      bf16x8 bfr[4];
      if (ci < c) {
        const u16* src = e + (size_t)memL[w][ci] * ND;
        #pragma unroll
        for (int ks = 0; ks < 4; ++ks)
          bfr[ks] = *(const bf16x8*)(src + ks * 32 + lg * 8);
      } else {
        #pragma unroll
        for (int ks = 0; ks < 4; ++ks) bfr[ks] = (bf16x8)0;
      }
      f32x4 acc;
      #pragma unroll
      for (int r = 0; r < 4; ++r) acc[r] = 0.f;
      #pragma unroll
      for (int ks = 0; ks < 4; ++ks)
        acc = __builtin_amdgcn_mfma_f32_16x16x32_bf16(af[ks], bfr[ks], acc, 0, 0, 0);

      #pragma unroll
      for (int r = 0; r < 4; ++r) {
        const int R = rb * 16 + lg * 4 + r;
        const int Cj = cb * 16 + lr_;
        const bool ok = (R < c) && (Cj < c) && (R != Cj);
        const float sv = acc[r];
        float xn = fmaf(sv * sv, G2, NEG_C);
        xn = (sv > -0.25f) ? xn : 0.f;
        corr[r] += ok ? fexp2(xn) : 0.f;
        if (ok) {
          const float t1 = 1.25f - sv;
          const float xp = G2 * fmaxf(t1, 0.f) * (t1 - 0.5f);
          if (xp > mp[r]) { sp[r] = sp[r] * fexp2(mp[r] - xp) + 1.f; mp[r] = xp; }
          else sp[r] += fexp2(xp - mp[r]);
        }
      }
    }
    // reduce over the 16 column-lanes
    #pragma unroll
    for (int r = 0; r < 4; ++r) {
      #pragma unroll
      for (int off = 1; off < 16; off <<= 1) {
        corr[r] += __shfl_xor(corr[r], off);
        const float m2 = __shfl_xor(mp[r], off), s2 = __shfl_xor(sp[r], off);
        const float M = fmaxf(mp[r], m2);
        const float t1 = sp[r] * fexp2(mp[r] - M);  // exp2(-1e30)=0 handles empties
        const float t2 = s2 * fexp2(m2 - M);
        mp[r] = M; sp[r] = t1 + t2;
      }
    }
    if (lr_ == 0) {
      #pragma unroll
      for (int r = 0; r < 4; ++r) {
        const int R = rb * 16 + lg * 4 + r;
        if (R < c) {
          float* o = poscorr + (size_t)memL[w][R] * 4;
          o[0] = mp[r]; o[1] = sp[r]; o[2] = corr[r]; o[3] = (float)(c - 1);
        }
      }
    }
  }
}

// ---- per-row finish: subtract correction, softplus, reduce ----------------
__global__ void k_rows(const float* __restrict__ part,
                       const float* __restrict__ poscorr,
                       float* __restrict__ bsum) {
  const int row = blockIdx.x * 256 + threadIdx.x;
  const float4* pr = reinterpret_cast<const float4*>(part + (size_t)row * NT);
  float sn = 0.f;
  #pragma unroll
  for (int q = 0; q < NT / 4; ++q) {
    const float4 v = pr[q];
    sn += v.x + v.y + v.z + v.w;
  }
  const float4 pc = *reinterpret_cast<const float4*>(poscorr + (size_t)row * 4);
  const int npi = (int)(pc.w + 0.5f);
  const bool valid = (npi > 0) && (npi < NB - 1);
  float val = 0.f;
  if (valid) {
    const float snn = fmaxf(sn - pc.z, 1e-30f);
    const float lp = LN2F * (pc.x + log2f(pc.y));
    const float ln_ = LN2F * log2f(snn);
    const float x = lp + ln_;
    val = fmaxf(x, 0.f) + log1pf(expf(-fabsf(x)));  // stable softplus
  }
  float cnt = valid ? 1.f : 0.f;
  val = wave_sum_f(val);
  cnt = wave_sum_f(cnt);
  __shared__ float svals[4], scnts[4];
  const int l = threadIdx.x & 63, w = threadIdx.x >> 6;
  if (l == 0) { svals[w] = val; scnts[w] = cnt; }
  __syncthreads();
  if (threadIdx.x == 0) {
    bsum[blockIdx.x * 2 + 0] = svals[0] + svals[1] + svals[2] + svals[3];
    bsum[blockIdx.x * 2 + 1] = scnts[0] + scnts[1] + scnts[2] + scnts[3];
  }
}

__global__ void k_final(const float* __restrict__ bsum, float* __restrict__ out) {
  const int t = threadIdx.x;
  float s = 0.f, c = 0.f;
  if (t < 32) { s = bsum[t * 2]; c = bsum[t * 2 + 1]; }
  s = wave_sum_f(s);
  c = wave_sum_f(c);
  if (t == 0) out[0] = s / fmaxf(c, 1.f);
}

extern "C" void kernel_launch(void* const* d_in, const int* in_sizes, int n_in,
                              void* d_out, int out_size, void* d_ws, size_t ws_size,
                              hipStream_t stream) {
  const float* emb = (const float*)d_in[0];
  const int* labels = (const int*)d_in[1];
  float* out = (float*)d_out;
  char* ws = (char*)d_ws;

  float* part    = (float*)(ws + 0);         // 8192*64*4      = 2097152
  float* poscorr = (float*)(ws + 2097152);   // 8192*4*4       = 131072
  u16*   ebf     = (u16*)  (ws + 2228224);   // 8192*128*2     = 2097152
  int*   ccount  = (int*)  (ws + 4325376);   // 16*512*4       = 32768
  int*   cmem    = (int*)  (ws + 4358144);   // 16*512*16*4    = 524288
  float* bsum    = (float*)(ws + 4882432);   // 64*4

  k_prep_lists<<<1040, 512, 0, stream>>>(emb, labels, ebf, ccount, cmem);
  k_main <<<(NT * (NT + 1)) / 2, 256, 0, stream>>>(ebf, part);
  k_pos  <<<NLAB / 4, 256, 0, stream>>>(ebf, ccount, cmem, poscorr);
  k_rows <<<NB / 256, 256, 0, stream>>>(part, poscorr, bsum);
  k_final<<<1, 64, 0, stream>>>(bsum, out);
}

// Round 9
// 46.002 us; speedup vs baseline: 7.6511x; 1.3328x over previous
//
#include <hip/hip_runtime.h>
#include <math.h>

#define NB 8192
#define ND 128
#define NT 64        // number of 128-row tiles
#define NTRI 2080    // NT*(NT+1)/2 upper-triangle tile pairs
#define NLAB 512
#define MAXM 64

typedef unsigned short u16;
typedef unsigned int u32;
typedef __attribute__((ext_vector_type(8))) short bf16x8;
typedef __attribute__((ext_vector_type(4))) float f32x4;

#define G2 369.3299304675746f         // gamma * log2(e)
#define NEG_C (-23.083120654223414f)  // -G2/16
#define SENT (-1e30f)
#define LN2F 0.6931471805599453f

static __device__ __forceinline__ void gload16(const void* g, void* l) {
  __builtin_amdgcn_global_load_lds(
      (const __attribute__((address_space(1))) u32*)g,
      (__attribute__((address_space(3))) u32*)l, 16, 0, 0);
}

static __device__ __forceinline__ float fexp2(float x) {
  return __builtin_amdgcn_exp2f(x);
}

static __device__ __forceinline__ u16 f2bf(float f) {
  u32 u = __float_as_uint(f);
  u32 r = (u + 0x7FFF + ((u >> 16) & 1)) >> 16;   // RNE
  return (u16)r;
}

static __device__ __forceinline__ float wave_sum_f(float v) {
  #pragma unroll
  for (int off = 1; off < 64; off <<= 1) v += __shfl_xor(v, off);
  return v;
}

// ---- k1: normalize rows + cast to bf16; reset tail counter ----------------
__global__ __launch_bounds__(512) void k_prep(const float* __restrict__ emb,
                                              u16* __restrict__ e,
                                              int* __restrict__ counter) {
  if (blockIdx.x == 0 && threadIdx.x == 0) counter[0] = 0;
  const int l = threadIdx.x & 63;
  const int w = threadIdx.x >> 6;
  const int row = blockIdx.x * 8 + w;
  const float2 v = reinterpret_cast<const float2*>(emb)[(size_t)row * 64 + l];
  float ss = wave_sum_f(v.x * v.x + v.y * v.y);
  const float inv = 1.0f / fmaxf(sqrtf(ss), 1e-12f);
  ushort2 o;
  o.x = f2bf(v.x * inv);
  o.y = f2bf(v.y * inv);
  reinterpret_cast<ushort2*>(e)[(size_t)row * 64 + l] = o;
}

// ---- k2: blocks 0..NTRI-1 = upper-triangle sim tiles; rest = per-label pos
__global__ __launch_bounds__(256, 3) void k_mainpos(const u16* __restrict__ e,
                                                    const int* __restrict__ labels,
                                                    float* __restrict__ part,
                                                    float* __restrict__ poscorr) {
  __shared__ __align__(16) char S[33792];   // 33 KB: B tiles / labels+memL
  const int bid = blockIdx.x;
  const int tid = threadIdx.x;
  const int l = tid & 63;
  const int w = tid >> 6;
  const int lr_ = l & 15;
  const int lg = l >> 4;

  if (bid < NTRI) {
    // ================= triangle sim tiles (bit-identical to round 7) =======
    int ti = (int)((129.0f - sqrtf(16641.0f - 8.0f * (float)bid)) * 0.5f);
    if (ti > NT - 1) ti = NT - 1;
    if (ti < 0) ti = 0;
    #define PRE(t) ((t) * NT - ((t) * ((t) - 1)) / 2)
    while (PRE(ti + 1) <= bid) ++ti;
    while (PRE(ti) > bid) --ti;
    const int tj = ti + (bid - PRE(ti));
    #undef PRE
    const int row0 = ti * 128;
    const int col0 = tj * 128;
    const bool diag = (ti == tj);
    char* Bh[2] = { S, S + 16384 };

    // A fragments in registers: rows row0 + w*32 + m*16 + lr_
    bf16x8 af[2][4];
    #pragma unroll
    for (int m = 0; m < 2; ++m)
      #pragma unroll
      for (int ks = 0; ks < 4; ++ks)
        af[m][ks] = *(const bf16x8*)(e + (size_t)(row0 + w * 32 + m * 16 + lr_) * ND +
                                     ks * 32 + lg * 8);

    // stage half 0 (swizzled source, linear LDS dest)
    #pragma unroll
    for (int i = 0; i < 4; ++i) {
      const int rr = w * 16 + i * 4 + lg;
      gload16(e + (size_t)(col0 + rr) * ND + (lr_ ^ (rr & 15)) * 8,
              Bh[0] + w * 4096 + i * 1024);
    }

    float sn[8], colp[8];
    #pragma unroll
    for (int q = 0; q < 8; ++q) { sn[q] = 0.f; colp[q] = 0.f; }

    __syncthreads();   // half 0 landed

    // stage half 1; lands during half-0 compute
    #pragma unroll
    for (int i = 0; i < 4; ++i) {
      const int rr = w * 16 + i * 4 + lg;
      gload16(e + (size_t)(col0 + 64 + rr) * ND + (lr_ ^ (rr & 15)) * 8,
              Bh[1] + w * 4096 + i * 1024);
    }

    #pragma unroll
    for (int h = 0; h < 2; ++h) {
      f32x4 acc[2][4];
      #pragma unroll
      for (int m = 0; m < 2; ++m)
        #pragma unroll
        for (int n = 0; n < 4; ++n)
          #pragma unroll
          for (int q = 0; q < 4; ++q) acc[m][n][q] = 0.f;

      #pragma unroll
      for (int ks = 0; ks < 4; ++ks) {
        const int kslot = (ks * 4 + lg) ^ lr_;   // read-side swizzle
        bf16x8 bfr[4];
        #pragma unroll
        for (int n = 0; n < 4; ++n)
          bfr[n] = *(const bf16x8*)(Bh[h] + (n * 16 + lr_) * 256 + kslot * 16);
        #pragma unroll
        for (int m = 0; m < 2; ++m)
          #pragma unroll
          for (int n = 0; n < 4; ++n)
            acc[m][n] = __builtin_amdgcn_mfma_f32_16x16x32_bf16(af[m][ks], bfr[n],
                                                                acc[m][n], 0, 0, 0);
      }

      // epilogue: ev feeds row sums and (by symmetry) column sums
      #pragma unroll
      for (int m = 0; m < 2; ++m) {
        #pragma unroll
        for (int n = 0; n < 4; ++n) {
          const bool dmn = diag && (w * 32 + m * 16 == h * 64 + n * 16);
          float scc = 0.f;
          #pragma unroll
          for (int j = 0; j < 4; ++j) {
            const float sv = acc[m][n][j];
            float xn = fmaf(sv * sv, G2, NEG_C);
            xn = (sv > -0.25f) ? xn : 0.f;
            if (dmn) xn = (lr_ == lg * 4 + j) ? SENT : xn;  // drop true diagonal
            const float ev = fexp2(xn);
            sn[m * 4 + j] += ev;
            scc += ev;
          }
          colp[h * 4 + n] += scc;
        }
      }
      if (h == 0) __syncthreads();   // half 1 landed
    }

    // row sums: reduce over 16 column-lanes, write slot tj
    #pragma unroll
    for (int q = 0; q < 8; ++q) {
      #pragma unroll
      for (int off = 1; off < 16; off <<= 1) sn[q] += __shfl_xor(sn[q], off);
    }
    if (lr_ == 0) {
      #pragma unroll
      for (int m = 0; m < 2; ++m)
        #pragma unroll
        for (int j = 0; j < 4; ++j) {
          const int row = row0 + w * 32 + m * 16 + lg * 4 + j;
          part[(size_t)row * NT + tj] = sn[m * 4 + j];
        }
    }

    // column sums (non-diag): reduce lg groups, cross-wave via LDS
    if (!diag) {
      #pragma unroll
      for (int q = 0; q < 8; ++q) {
        colp[q] += __shfl_xor(colp[q], 16);
        colp[q] += __shfl_xor(colp[q], 32);
      }
      __syncthreads();                   // all MFMA LDS reads done
      float* colbuf = (float*)S;
      if (l < 16) {
        #pragma unroll
        for (int q = 0; q < 8; ++q)
          colbuf[w * 128 + (q >> 2) * 64 + (q & 3) * 16 + lr_] = colp[q];
      }
      __syncthreads();
      if (tid < 128) {
        const float cs_ = colbuf[tid] + colbuf[128 + tid] +
                          colbuf[256 + tid] + colbuf[384 + tid];
        part[(size_t)(col0 + tid) * NT + ti] = cs_;
      }
    }
  } else {
    // ================= per-label positives + same-label correction =========
    int* lab = (int*)S;                        // 8192 ints = 32 KB
    for (int i = tid; i < NB / 4; i += 256)
      ((int4*)lab)[i] = ((const int4*)labels)[i];
    __syncthreads();

    const int L = (bid - NTRI) * 4 + w;        // one wave per label
    int* memL = (int*)(S + 32768) + w * MAXM;

    // build ordered member list via ballot rounds (ascending index order)
    int cnt = 0;
    for (int base = 0; base < NB; base += 64) {
      const int lv = lab[base + l];
      const unsigned long long mk = __ballot(lv == L);
      if (lv == L) {
        const int pos = __popcll(mk & ((1ull << l) - 1));
        if (cnt + pos < MAXM) memL[cnt + pos] = base + l;
      }
      cnt += __popcll(mk);
    }
    int c = cnt > MAXM ? MAXM : cnt;
    __syncthreads();   // memL visible across lanes of each wave

    const int nt = (c + 15) >> 4;
    for (int rb = 0; rb < nt; ++rb) {
      const int ri = rb * 16 + lr_;
      bf16x8 af[4];
      if (ri < c) {
        const u16* src = e + (size_t)memL[ri] * ND;
        #pragma unroll
        for (int ks = 0; ks < 4; ++ks)
          af[ks] = *(const bf16x8*)(src + ks * 32 + lg * 8);
      } else {
        #pragma unroll
        for (int ks = 0; ks < 4; ++ks) af[ks] = (bf16x8)0;
      }
      float corr[4], mp[4], sp[4];
      #pragma unroll
      for (int r = 0; r < 4; ++r) { corr[r] = 0.f; mp[r] = SENT; sp[r] = 0.f; }

      for (int cb = 0; cb < nt; ++cb) {
        const int ci = cb * 16 + lr_;
        bf16x8 bfr[4];
        if (ci < c) {
          const u16* src = e + (size_t)memL[ci] * ND;
          #pragma unroll
          for (int ks = 0; ks < 4; ++ks)
            bfr[ks] = *(const bf16x8*)(src + ks * 32 + lg * 8);
        } else {
          #pragma unroll
          for (int ks = 0; ks < 4; ++ks) bfr[ks] = (bf16x8)0;
        }
        f32x4 acc;
        #pragma unroll
        for (int r = 0; r < 4; ++r) acc[r] = 0.f;
        #pragma unroll
        for (int ks = 0; ks < 4; ++ks)
          acc = __builtin_amdgcn_mfma_f32_16x16x32_bf16(af[ks], bfr[ks], acc, 0, 0, 0);

        #pragma unroll
        for (int r = 0; r < 4; ++r) {
          const int R = rb * 16 + lg * 4 + r;
          const int Cj = cb * 16 + lr_;
          const bool ok = (R < c) && (Cj < c) && (R != Cj);
          const float sv = acc[r];
          float xn = fmaf(sv * sv, G2, NEG_C);
          xn = (sv > -0.25f) ? xn : 0.f;
          corr[r] += ok ? fexp2(xn) : 0.f;
          if (ok) {
            const float t1 = 1.25f - sv;
            const float xp = G2 * fmaxf(t1, 0.f) * (t1 - 0.5f);
            if (xp > mp[r]) { sp[r] = sp[r] * fexp2(mp[r] - xp) + 1.f; mp[r] = xp; }
            else sp[r] += fexp2(xp - mp[r]);
          }
        }
      }
      #pragma unroll
      for (int r = 0; r < 4; ++r) {
        #pragma unroll
        for (int off = 1; off < 16; off <<= 1) {
          corr[r] += __shfl_xor(corr[r], off);
          const float m2 = __shfl_xor(mp[r], off), s2 = __shfl_xor(sp[r], off);
          const float M = fmaxf(mp[r], m2);
          const float t1 = sp[r] * fexp2(mp[r] - M);  // exp2(-1e30)=0 for empties
          const float t2 = s2 * fexp2(m2 - M);
          mp[r] = M; sp[r] = t1 + t2;
        }
      }
      if (lr_ == 0) {
        #pragma unroll
        for (int r = 0; r < 4; ++r) {
          const int R = rb * 16 + lg * 4 + r;
          if (R < c) {
            float* o = poscorr + (size_t)memL[R] * 4;
            o[0] = mp[r]; o[1] = sp[r]; o[2] = corr[r]; o[3] = (float)(c - 1);
          }
        }
      }
    }
  }
}

// ---- k3: per-row finish + fused final scalar via arrival counter ----------
__global__ __launch_bounds__(256) void k_rowsfinal(const float* __restrict__ part,
                                                   const float* __restrict__ poscorr,
                                                   float* __restrict__ bsum,
                                                   int* __restrict__ counter,
                                                   float* __restrict__ out) {
  const int bid = blockIdx.x;
  const int tid = threadIdx.x;
  const int l = tid & 63, w = tid >> 6;
  const int row = bid * 256 + tid;
  const float4* pr = reinterpret_cast<const float4*>(part + (size_t)row * NT);
  float sn = 0.f;
  #pragma unroll
  for (int q = 0; q < NT / 4; ++q) {
    const float4 v = pr[q];
    sn += v.x + v.y + v.z + v.w;
  }
  const float4 pc = *reinterpret_cast<const float4*>(poscorr + (size_t)row * 4);
  const int npi = (int)(pc.w + 0.5f);
  const bool valid = (npi > 0) && (npi < NB - 1);
  float val = 0.f;
  if (valid) {
    const float snn = fmaxf(sn - pc.z, 1e-30f);
    const float lp = LN2F * (pc.x + log2f(pc.y));
    const float ln_ = LN2F * log2f(snn);
    const float x = lp + ln_;
    val = fmaxf(x, 0.f) + log1pf(expf(-fabsf(x)));  // stable softplus
  }
  float cnt = valid ? 1.f : 0.f;
  val = wave_sum_f(val);
  cnt = wave_sum_f(cnt);
  __shared__ float svals[4], scnts[4];
  __shared__ int lastflag;
  if (l == 0) { svals[w] = val; scnts[w] = cnt; }
  __syncthreads();
  if (tid == 0) {
    bsum[bid * 2 + 0] = svals[0] + svals[1] + svals[2] + svals[3];
    bsum[bid * 2 + 1] = scnts[0] + scnts[1] + scnts[2] + scnts[3];
    __threadfence();                       // publish bsum device-wide
    const int prev = atomicAdd(counter, 1);
    lastflag = (prev == 31);
  }
  __syncthreads();
  if (lastflag && w == 0) {
    __threadfence();                       // acquire all blocks' bsum
    float s = 0.f, c = 0.f;
    if (l < 32) {
      volatile const float* vb = (volatile const float*)bsum;
      s = vb[l * 2];
      c = vb[l * 2 + 1];
    }
    s = wave_sum_f(s);
    c = wave_sum_f(c);
    if (l == 0) out[0] = s / fmaxf(c, 1.f);
  }
}

extern "C" void kernel_launch(void* const* d_in, const int* in_sizes, int n_in,
                              void* d_out, int out_size, void* d_ws, size_t ws_size,
                              hipStream_t stream) {
  const float* emb = (const float*)d_in[0];
  const int* labels = (const int*)d_in[1];
  float* out = (float*)d_out;
  char* ws = (char*)d_ws;

  float* part    = (float*)(ws + 0);         // 8192*64*4  = 2097152
  float* poscorr = (float*)(ws + 2097152);   // 8192*4*4   = 131072
  u16*   ebf     = (u16*)  (ws + 2228224);   // 8192*128*2 = 2097152
  float* bsum    = (float*)(ws + 4325376);   // 256 B
  int*   counter = (int*)  (ws + 4325632);   // 4 B

  k_prep<<<NB / 8, 512, 0, stream>>>(emb, ebf, counter);
  k_mainpos<<<NTRI + NLAB / 4, 256, 0, stream>>>(ebf, labels, part, poscorr);
  k_rowsfinal<<<NB / 256, 256, 0, stream>>>(part, poscorr, bsum, counter, out);
}